// Round 7
// baseline (540.169 us; speedup 1.0000x reference)
//
#include <hip/hip_runtime.h>
#include <math.h>

#define NS 20000
#define TT 6890
#define TPAD 6912
#define FE 128
#define EDG 640000
#define DEG 32

#define RPB 80            // rows per block (5 rowsets) -> 250 row-blocks exact
#define NCB 4             // col-blocks
#define CBW 1728          // cols per col-block (27 x 64-col strips)
#define NH 5              // rowsets per block
#define PBLK 313          // proc grid = (NS*4+255)/256

typedef __attribute__((ext_vector_type(8))) short short8;     // 8 bf16
typedef __attribute__((ext_vector_type(4))) float floatx4;    // MFMA C/D
typedef __attribute__((ext_vector_type(4))) int i32x4;        // asm ds_read dst
typedef unsigned int uint;

__device__ __forceinline__ unsigned short f2bf(float f) {
  unsigned int u = __float_as_uint(f);
  return (unsigned short)((u + 0x7fffu + ((u >> 16) & 1u)) >> 16);  // RNE
}

// exact insertion of t into ascending sorted-6 (keep smallest 6): 6 VALU ops
__device__ __forceinline__ uint med3u(uint a, uint b, uint c) {
  uint d;
  asm("v_med3_u32 %0, %1, %2, %3" : "=v"(d) : "v"(a), "v"(b), "v"(c));
  return d;
}
__device__ __forceinline__ void ins6(uint* a, uint t) {
  a[5] = med3u(a[4], a[5], t);
  a[4] = med3u(a[3], a[4], t);
  a[3] = med3u(a[2], a[3], t);
  a[2] = med3u(a[1], a[2], t);
  a[1] = med3u(a[0], a[1], t);
  a[0] = min(a[0], t);
}
__device__ __forceinline__ void ins12(uint* a, uint t) {
  a[11] = med3u(a[10], a[11], t);
  a[10] = med3u(a[9], a[10], t);
  a[9]  = med3u(a[8], a[9], t);
  a[8]  = med3u(a[7], a[8], t);
  a[7]  = med3u(a[6], a[7], t);
  a[6]  = med3u(a[5], a[6], t);
  a[5]  = med3u(a[4], a[5], t);
  a[4]  = med3u(a[3], a[4], t);
  a[3]  = med3u(a[2], a[3], t);
  a[2]  = med3u(a[1], a[2], t);
  a[1]  = med3u(a[0], a[1], t);
  a[0]  = min(a[0], t);
}

// ---------------- K0: col-major swizzled bf16 records + tn + scaled tn256 ----------------
// Also zeroes the device-side sync counters (cnt[250] + cnt2) each launch.
__global__ void tn_cast_kernel(const float* __restrict__ tf, float* __restrict__ tn,
                               float* __restrict__ tn256,
                               unsigned short* __restrict__ tfbx,
                               uint* __restrict__ cntp) {
  int gid = blockIdx.x * blockDim.x + threadIdx.x;
  if (gid < 251) cntp[gid] = 0;
  int w = gid >> 6;
  int lane = gid & 63;
  if (w >= TPAD) return;
  unsigned short* base = tfbx + (size_t)w * 128;
  int jj = lane >> 2;
  int soff = ((jj ^ (w & 7)) << 3) + (lane & 3) * 2;
  if (w < TT) {
    const float* p = tf + (size_t)w * FE;
    float a = p[lane];
    float b = p[lane + 64];
    float s = a * a + b * b;
#pragma unroll
    for (int off = 32; off > 0; off >>= 1) s += __shfl_xor(s, off);
    if (lane == 0) { tn[w] = s; tn256[w] = -0.5f * (s + 256.0f); }
    ushort2 o;
    o.x = f2bf(p[2 * lane]);
    o.y = f2bf(p[2 * lane + 1]);
    *reinterpret_cast<ushort2*>(base + soff) = o;
  } else {
    if (lane == 0) { tn[w] = 1e30f; tn256[w] = -1.5e38f; }  // pads never win
    ushort2 z; z.x = 0; z.y = 0;
    *reinterpret_cast<ushort2*>(base + soff) = z;
  }
}

// ---------------- K1: 80-row GEMM + top-6 + FUSED per-row merge (last arriver) ----------------
// R7: topk main loop reverted to its best config (R5: A-prefetch, (256,2)).
// merge_kernel is fused as a tail: the 4 (rb,cb=0..3) blocks each write their
// pkall slice; 4th arriver (atomicAdd on cnt[rb], last-block idiom — no spin,
// no residency assumption) rescores the bf16-top-24 of the union-48 in fp32
// and writes pred for its 80 rows. Arithmetic identical to the old merge.
union SmemK1 {
  unsigned short Bs[RPB * 128];   // 20480 B staged source rows
  uint pk[RPB][24];               // 7680 B epilogue overlay
  struct { uint kk[4][24]; float sv[4][24]; int sc[4][24]; } t;  // merge tail
};

__device__ __forceinline__ void mfma4_sel(
    short8 a0, short8 a1, short8 a2, short8 a3,
    short8 b0, short8 b1, short8 b2, short8 b3,
    float4 t4, const uint* ckr, uint* kqh) {
  floatx4 acc = (floatx4){t4.x, t4.y, t4.z, t4.w};
  acc = __builtin_amdgcn_mfma_f32_16x16x32_bf16(a0, b0, acc, 0, 0, 0);
  acc = __builtin_amdgcn_mfma_f32_16x16x32_bf16(a1, b1, acc, 0, 0, 0);
  acc = __builtin_amdgcn_mfma_f32_16x16x32_bf16(a2, b2, acc, 0, 0, 0);
  acc = __builtin_amdgcn_mfma_f32_16x16x32_bf16(a3, b3, acc, 0, 0, 0);
#pragma unroll
  for (int r = 0; r < 4; ++r) {
    uint t = (__float_as_uint(acc[r]) & 0xFFFFE000u) | ckr[r];  // v_and_or
    ins6(kqh, t);
  }
}

__global__ __launch_bounds__(256, 2) void topk_kernel(
    const float* __restrict__ sf, const float* __restrict__ tf,
    const unsigned short* __restrict__ tfbx,
    const float* __restrict__ tn256, const float* __restrict__ tn,
    const float* __restrict__ tp, uint* __restrict__ pkall,
    float* __restrict__ pred, uint* __restrict__ cnt) {
  __shared__ SmemK1 u;
  __shared__ int lastFlag;
  const int tid = threadIdx.x;
  const int lane = tid & 63;
  const int wv = tid >> 6;
  const int q = lane >> 4;
  const int m = lane & 15;
  const int rb = (int)blockIdx.x >> 2;
  const int cb = (int)blockIdx.x & 3;
  const int row0 = rb * RPB;          // exact: 250*80 = 20000
  const int cbase = cb * CBW;

  // one-time stage: 80 source rows -> Bs (bf16, swizzled)
#pragma unroll
  for (int t = 0; t < 5; ++t) {
    int c = tid + t * 256;
    int rr = c >> 4, jj = c & 15;
    const float* src = sf + (size_t)(row0 + rr) * FE + jj * 8;
    float4 f0 = *reinterpret_cast<const float4*>(src);
    float4 f1 = *reinterpret_cast<const float4*>(src + 4);
    union { unsigned short us[8]; uint4 v; } tt;
    tt.us[0] = f2bf(f0.x); tt.us[1] = f2bf(f0.y);
    tt.us[2] = f2bf(f0.z); tt.us[3] = f2bf(f0.w);
    tt.us[4] = f2bf(f1.x); tt.us[5] = f2bf(f1.y);
    tt.us[6] = f2bf(f1.z); tt.us[7] = f2bf(f1.w);
    *reinterpret_cast<uint4*>(u.Bs + rr * 128 + ((jj ^ (rr & 7)) << 3)) = tt.v;
  }

  uint kq[NH][6];
#pragma unroll
  for (int h = 0; h < NH; ++h)
#pragma unroll
    for (int k = 0; k < 6; ++k) kq[h][k] = 0xFFFFFFFFu;

  int rdB[4];
  int aoff[4];
  const int ax = m & 7;
#pragma unroll
  for (int ks = 0; ks < 4; ++ks) {
    int slot = (ks * 4 + q) ^ ax;
    rdB[ks] = m * 128 + (slot << 3);
    aoff[ks] = slot << 3;
  }
  const unsigned short* abase = tfbx + (size_t)(cbase + wv * 16 + m) * 128;
  const uint ck0 = (uint)(cbase + wv * 16 + q * 4);

  __syncthreads();

  // forced hoist: 20 asm ds_read_b128 into named regs (main loop LDS-free)
  short8 bf[NH][4];
  {
    uint bs0 = (uint)(uintptr_t)(&u.Bs[0]);
    uint adr[4];
#pragma unroll
    for (int ks = 0; ks < 4; ++ks) adr[ks] = bs0 + (uint)(rdB[ks] * 2);
#pragma unroll
    for (int h = 0; h < NH; ++h) {
#pragma unroll
      for (int ks = 0; ks < 4; ++ks) {
        union { i32x4 i; short8 s; } t;
        asm volatile("ds_read_b128 %0, %1 offset:%2"
                     : "=v"(t.i) : "v"(adr[ks]), "i"(h * 4096));
        bf[h][ks] = t.s;
      }
    }
    asm volatile("s_waitcnt lgkmcnt(0)" ::: "memory");
    __builtin_amdgcn_sched_barrier(0);
  }

  // main loop: no LDS, A direct from global (L2), prefetched 1 strip ahead
  short8 a0 = *reinterpret_cast<const short8*>(abase + aoff[0]);
  short8 a1 = *reinterpret_cast<const short8*>(abase + aoff[1]);
  short8 a2 = *reinterpret_cast<const short8*>(abase + aoff[2]);
  short8 a3 = *reinterpret_cast<const short8*>(abase + aoff[3]);
  float4 t4 = *reinterpret_cast<const float4*>(tn256 + cbase + wv * 16 + q * 4);

  for (int s = 0; s < 27; ++s) {
    const int sn = (s < 26) ? s + 1 : 26;     // clamp: avoid OOB prefetch
    const unsigned short* apn = abase + (size_t)sn * 8192;
    short8 na0 = *reinterpret_cast<const short8*>(apn + aoff[0]);
    short8 na1 = *reinterpret_cast<const short8*>(apn + aoff[1]);
    short8 na2 = *reinterpret_cast<const short8*>(apn + aoff[2]);
    short8 na3 = *reinterpret_cast<const short8*>(apn + aoff[3]);
    float4 nt4 = *reinterpret_cast<const float4*>(
        tn256 + cbase + sn * 64 + wv * 16 + q * 4);
    uint ckr[4];
    const uint cks = ck0 + (uint)(s * 64);
#pragma unroll
    for (int r = 0; r < 4; ++r) ckr[r] = cks + (uint)r;
#pragma unroll
    for (int h = 0; h < NH; ++h)
      mfma4_sel(a0, a1, a2, a3, bf[h][0], bf[h][1], bf[h][2], bf[h][3],
                t4, ckr, kq[h]);
    a0 = na0; a1 = na1; a2 = na2; a3 = na3; t4 = nt4;
  }

  // merge across the 4 q-lanes via shfl butterfly (exact top-6 of 24)
#pragma unroll
  for (int h = 0; h < NH; ++h) {
#pragma unroll
    for (int st = 16; st <= 32; st <<= 1) {
      uint inc[6];
#pragma unroll
      for (int k = 0; k < 6; ++k) inc[k] = __shfl_xor(kq[h][k], st);
#pragma unroll
      for (int k = 0; k < 6; ++k) ins6(kq[h], inc[k]);
    }
  }
  __syncthreads();   // Bs dead; overlay epilogue
  if (q == 0) {
#pragma unroll
    for (int h = 0; h < NH; ++h)
#pragma unroll
      for (int k = 0; k < 6; ++k) u.pk[h * 16 + m][wv * 6 + k] = kq[h][k];
  }
  __syncthreads();

  // per row: exact top-12 of the 24 -> pkall[row][cb*12..]
  if (tid < RPB) {
    uint md[12];
#pragma unroll
    for (int k = 0; k < 12; ++k) md[k] = 0xFFFFFFFFu;
    for (int j = 0; j < 24; ++j) ins12(md, u.pk[tid][j]);
    uint* dst = pkall + (size_t)(row0 + tid) * 48 + cb * 12;
#pragma unroll
    for (int k = 0; k < 12; ++k) dst[k] = md[k];
  }

  // ---- fused merge: last arriver of the 4 cb-blocks for this rb ----
  __syncthreads();              // all pkall stores drained (barrier waits vmcnt)
  if (tid == 0) {
    __threadfence();            // release this block's pkall slice
    lastFlag = (atomicAdd(&cnt[rb], 1u) == 3u) ? 1 : 0;
  }
  __syncthreads();
  if (!lastFlag) return;
  __threadfence();              // acquire the other 3 blocks' slices

  for (int rr = wv; rr < RPB; rr += 4) {   // 20 rows per wave
    const int row = row0 + rr;
    uint k0 = 0xFFFFFFFFu;
    if (lane < 48) k0 = pkall[(size_t)row * 48 + lane];
    int rk = 0;
    for (int j = 0; j < 48; ++j) {
      uint a = __shfl(k0, j);
      rk += (a < k0) ? 1 : 0;              // keys unique (distinct col bits)
    }
    if (lane < 48 && rk < 24) u.t.kk[wv][rk] = k0;  // compact top-24 by rank
    const int g = lane >> 2;
    const int c4 = lane & 3;
    const float* srow = sf + (size_t)row * FE;
    float4 sfc[8];
#pragma unroll
    for (int it = 0; it < 8; ++it)
      sfc[it] = *reinterpret_cast<const float4*>(srow + (it * 4 + c4) * 4);
#pragma unroll
    for (int p = 0; p < 2; ++p) {
      const int j = p * 16 + g;
      if (j < 24) {
        const int col = (int)(u.t.kk[wv][j] & 0x1FFFu);
        const float* trow = tf + (size_t)col * FE;
        float acc = 0.f;
#pragma unroll
        for (int it = 0; it < 8; ++it) {
          float4 bv = *reinterpret_cast<const float4*>(trow + (it * 4 + c4) * 4);
          float4 av = sfc[it];
          acc += av.x * bv.x + av.y * bv.y + av.z * bv.z + av.w * bv.w;
        }
        acc += __shfl_xor(acc, 1);
        acc += __shfl_xor(acc, 2);
        if (c4 == 0) {                     // rank j is a unique slot
          u.t.sv[wv][j] = tn[col] - 2.f * acc;
          u.t.sc[wv][j] = col;
        }
      }
    }
    if (lane == 0) {
      float sd[6]; int sp6[6];
#pragma unroll
      for (int k = 0; k < 6; ++k) { sd[k] = 1e30f; sp6[k] = 0; }
      for (int j = 0; j < 24; ++j) {
        float v = u.t.sv[wv][j];
        if (v < sd[5]) {
          sd[5] = v; sp6[5] = j;
#pragma unroll
          for (int k = 4; k >= 0; --k) {
            if (sd[k + 1] < sd[k]) {
              float tvv = sd[k]; sd[k] = sd[k + 1]; sd[k + 1] = tvv;
              int tii = sp6[k]; sp6[k] = sp6[k + 1]; sp6[k + 1] = tii;
            }
          }
        }
      }
      float wgt[6]; float wsum = 0.f;
#pragma unroll
      for (int k = 0; k < 6; ++k) { wgt[k] = __expf(sd[0] - sd[k]); wsum += wgt[k]; }
      float inv = 1.f / wsum;
      float px = 0.f, py = 0.f, pz = 0.f;
#pragma unroll
      for (int k = 0; k < 6; ++k) {
        float scv = wgt[k] * inv;
        const float* qq = tp + (size_t)u.t.sc[wv][sp6[k]] * 3;
        px += scv * qq[0]; py += scv * qq[1]; pz += scv * qq[2];
      }
      pred[row * 3 + 0] = px;
      pred[row * 3 + 1] = py;
      pred[row * 3 + 2] = pz;
    }
  }
}

// ---------------- K2: Procrustes + FUSED dst (grid-wide counter barrier) ----------------
// 313 blocks, launch_bounds(256,2) caps regs<=256 -> >=2 blocks/CU -> 512>=313
// co-resident guaranteed -> the spin barrier cannot deadlock.
__global__ __launch_bounds__(256, 2) void proc_kernel(
    const int* __restrict__ colp, const float* __restrict__ pos,
    const float* __restrict__ pred, float* __restrict__ Rout,
    float* __restrict__ tout, float* __restrict__ qnorm,
    float* __restrict__ dout, uint* __restrict__ cnt2) {
  int t = blockIdx.x * blockDim.x + threadIdx.x;
  int i = t >> 2;
  int l = t & 3;
  const bool valid = (i < NS);
  const int ic = valid ? i : (NS - 1);     // clamp: uniform control flow
  int4 cia[2];
#pragma unroll
  for (int tt = 0; tt < 2; ++tt)
    cia[tt] = reinterpret_cast<const int4*>(colp + (size_t)ic * DEG + l * 8)[tt];
  const int* cidx = reinterpret_cast<const int*>(cia);

  double sp[3] = {0, 0, 0}, sq[3] = {0, 0, 0};
  double spq[3][3] = {{0, 0, 0}, {0, 0, 0}, {0, 0, 0}};
#pragma unroll
  for (int e = 0; e < 8; ++e) {
    int c = cidx[e];
    double p0 = pos[c * 3], p1 = pos[c * 3 + 1], p2 = pos[c * 3 + 2];
    double q0 = pred[c * 3], q1 = pred[c * 3 + 1], q2 = pred[c * 3 + 2];
    sp[0] += p0; sp[1] += p1; sp[2] += p2;
    sq[0] += q0; sq[1] += q1; sq[2] += q2;
    spq[0][0] += p0 * q0; spq[0][1] += p0 * q1; spq[0][2] += p0 * q2;
    spq[1][0] += p1 * q0; spq[1][1] += p1 * q1; spq[1][2] += p1 * q2;
    spq[2][0] += p2 * q0; spq[2][1] += p2 * q1; spq[2][2] += p2 * q2;
  }
#pragma unroll
  for (int mask = 1; mask <= 2; mask <<= 1) {
#pragma unroll
    for (int a = 0; a < 3; ++a) {
      sp[a] += __shfl_xor(sp[a], mask);
      sq[a] += __shfl_xor(sq[a], mask);
#pragma unroll
      for (int b = 0; b < 3; ++b) spq[a][b] += __shfl_xor(spq[a][b], mask);
    }
  }

  const double inv = 1.0 / 32.0;
  double A[3][3], sc[3], tcn[3];
  for (int a = 0; a < 3; ++a) {
    sc[a] = sp[a] * inv;
    tcn[a] = sq[a] * inv;
  }
  for (int a = 0; a < 3; ++a)
    for (int b = 0; b < 3; ++b) A[a][b] = spq[a][b] - sp[a] * sq[b] * inv;

  double S[3][3];
  for (int a = 0; a < 3; ++a)
    for (int b = 0; b < 3; ++b)
      S[a][b] = A[0][a] * A[0][b] + A[1][a] * A[1][b] + A[2][a] * A[2][b];
  double V[3][3] = {{1, 0, 0}, {0, 1, 0}, {0, 0, 1}};
  const int JP[3] = {0, 0, 1}, JQ[3] = {1, 2, 2};
  for (int sweep = 0; sweep < 6; ++sweep) {
    for (int r = 0; r < 3; ++r) {
      int p = JP[r], q = JQ[r];
      double apq = S[p][q];
      if (fabs(apq) < 1e-300) continue;
      double theta = (S[q][q] - S[p][p]) / (2.0 * apq);
      double t2 = copysign(1.0 / (fabs(theta) + sqrt(theta * theta + 1.0)), theta);
      double c = 1.0 / sqrt(t2 * t2 + 1.0);
      double s = t2 * c;
      double spp = S[p][p], sqq = S[q][q];
      S[p][p] = spp - t2 * apq;
      S[q][q] = sqq + t2 * apq;
      S[p][q] = 0.0; S[q][p] = 0.0;
      int k = 3 - p - q;
      double skp = S[k][p], skq = S[k][q];
      S[k][p] = S[p][k] = c * skp - s * skq;
      S[k][q] = S[q][k] = s * skp + c * skq;
      for (int mth = 0; mth < 3; ++mth) {
        double vp = V[mth][p], vq = V[mth][q];
        V[mth][p] = c * vp - s * vq;
        V[mth][q] = s * vp + c * vq;
      }
    }
  }
  double lam[3] = {S[0][0], S[1][1], S[2][2]};
  int i0 = 0, i1 = 1, i2 = 2, tmp;
  if (lam[i0] < lam[i1]) { tmp = i0; i0 = i1; i1 = tmp; }
  if (lam[i0] < lam[i2]) { tmp = i0; i0 = i2; i2 = tmp; }
  if (lam[i1] < lam[i2]) { tmp = i1; i1 = i2; i2 = tmp; }
  double v0[3] = {V[0][i0], V[1][i0], V[2][i0]};
  double v1[3] = {V[0][i1], V[1][i1], V[2][i1]};
  double v2[3] = {V[0][i2], V[1][i2], V[2][i2]};

  double Av0[3], Av1[3], Av2[3];
  for (int a = 0; a < 3; ++a) {
    Av0[a] = A[a][0] * v0[0] + A[a][1] * v0[1] + A[a][2] * v0[2];
    Av1[a] = A[a][0] * v1[0] + A[a][1] * v1[1] + A[a][2] * v1[2];
    Av2[a] = A[a][0] * v2[0] + A[a][1] * v2[1] + A[a][2] * v2[2];
  }
  double n0 = fmax(sqrt(Av0[0]*Av0[0] + Av0[1]*Av0[1] + Av0[2]*Av0[2]), 1e-300);
  double u0[3] = {Av0[0] / n0, Av0[1] / n0, Av0[2] / n0};
  double proj = u0[0]*Av1[0] + u0[1]*Av1[1] + u0[2]*Av1[2];
  double u1[3] = {Av1[0] - proj * u0[0], Av1[1] - proj * u0[1], Av1[2] - proj * u0[2]};
  double n1 = fmax(sqrt(u1[0]*u1[0] + u1[1]*u1[1] + u1[2]*u1[2]), 1e-300);
  u1[0] /= n1; u1[1] /= n1; u1[2] /= n1;
  double w[3] = {u0[1]*u1[2] - u0[2]*u1[1],
                 u0[2]*u1[0] - u0[0]*u1[2],
                 u0[0]*u1[1] - u0[1]*u1[0]};
  double dotw = Av2[0]*w[0] + Av2[1]*w[1] + Av2[2]*w[2];
  double sgn = (dotw < 0.0) ? -1.0 : 1.0;
  double detA = A[0][0]*(A[1][1]*A[2][2] - A[1][2]*A[2][1])
              - A[0][1]*(A[1][0]*A[2][2] - A[1][2]*A[2][0])
              + A[0][2]*(A[1][0]*A[2][1] - A[1][1]*A[2][0]);
  double d3 = ((detA < 0.0) ? -1.0 : 1.0) * sgn;

  double R[3][3];
  for (int a = 0; a < 3; ++a)
    for (int b = 0; b < 3; ++b)
      R[a][b] = u0[a]*v0[b] + u1[a]*v1[b] + d3 * w[a]*v2[b];

  if (valid && l == 0) {
    for (int a = 0; a < 3; ++a)
      for (int b = 0; b < 3; ++b) Rout[i * 9 + a * 3 + b] = (float)R[a][b];
    double tr_[3];
    for (int a = 0; a < 3; ++a) {
      tr_[a] = tcn[a] - (R[a][0]*sc[0] + R[a][1]*sc[1] + R[a][2]*sc[2]);
      tout[i * 3 + a] = (float)tr_[a];
    }
    double pxi = pos[i * 3], pyi = pos[i * 3 + 1], pzi = pos[i * 3 + 2];
    double r0 = R[0][0]*pxi + R[0][1]*pyi + R[0][2]*pzi + tr_[0] - pred[i * 3];
    double r1 = R[1][0]*pxi + R[1][1]*pyi + R[1][2]*pzi + tr_[1] - pred[i * 3 + 1];
    double r2 = R[2][0]*pxi + R[2][1]*pyi + R[2][2]*pzi + tr_[2] - pred[i * 3 + 2];
    qnorm[i] = (float)(r0 * r0 + r1 * r1 + r2 * r2);
  }

  // ---- grid-wide barrier (all 313 blocks co-resident by construction) ----
  __syncthreads();              // all qnorm stores drained
  if (threadIdx.x == 0) {
    __threadfence();            // release qnorm
    atomicAdd(cnt2, 1u);
    while (__hip_atomic_load(cnt2, __ATOMIC_ACQUIRE, __HIP_MEMORY_SCOPE_AGENT)
           < (uint)PBLK) {
      __builtin_amdgcn_s_sleep(2);
    }
  }
  __syncthreads();
  __threadfence();              // acquire all blocks' qnorm

  // ---- fused dst phase: per-node residual mean (same 4-lane mapping) ----
  {
    float s = 0.f;
#pragma unroll
    for (int e = 0; e < 8; ++e) s += qnorm[cidx[e]];
    s += __shfl_xor(s, 1);
    s += __shfl_xor(s, 2);
    if (valid && l == 0) dout[i] = s * (1.0f / 32.0f);
  }
}

extern "C" void kernel_launch(void* const* d_in, const int* in_sizes, int n_in,
                              void* d_out, int out_size, void* d_ws, size_t ws_size,
                              hipStream_t stream) {
  const float* sf  = (const float*)d_in[0];   // [N,128]
  const float* tf  = (const float*)d_in[1];   // [T,128]
  const float* tp  = (const float*)d_in[2];   // [T,3]
  const float* pos = (const float*)d_in[3];   // [N,3]
  const int*   ei  = (const int*)d_in[4];     // [2,E]
  float* out = (float*)d_out;                 // [N*9 | N*3 | N]
  char* ws = (char*)d_ws;
  // ws layout (~5.9 MB; qn aliases tfbx which is dead after topk):
  float*          tn    = (float*)(ws);                    // 27,648 B
  float*          tn256 = (float*)(ws + 28672);            // 27,648 B used
  uint*           cntp  = (uint*)(ws + 56320);             // 251 uints (spare)
  float*          pred  = (float*)(ws + 57344);            // 240,000 B
  uint*           pkall = (uint*)(ws + 297344);            // 20000*48*4 = 3,840,000 B
  unsigned short* tfbx  = (unsigned short*)(ws + 4137344); // 1,769,472 B
  float*          qn    = (float*)(ws + 4137344);          // alias (post-topk)
  const int* colp = ei + EDG;

  tn_cast_kernel<<<(TPAD * 64) / 256, 256, 0, stream>>>(tf, tn, tn256, tfbx, cntp);
  topk_kernel<<<(NS / RPB) * NCB, 256, 0, stream>>>(sf, tf, tfbx, tn256, tn, tp,
                                                    pkall, pred, cntp);
  proc_kernel<<<PBLK, 256, 0, stream>>>(colp, pos, pred, out, out + NS * 9, qn,
                                        out + NS * 12, cntp + 250);
}

// Round 8
// 354.406 us; speedup vs baseline: 1.5242x; 1.5242x over previous
//
#include <hip/hip_runtime.h>
#include <math.h>

#define NS 20000
#define TT 6890
#define TPAD 6912
#define FE 128
#define EDG 640000
#define DEG 32

#define RPB 80            // rows per block (5 rowsets) -> 250 row-blocks exact
#define NCB 4             // col-blocks
#define CBW 1728          // cols per col-block (27 x 64-col strips)
#define NH 5              // rowsets per block
#define PBLK 313          // proc grid = (NS*4+255)/256

typedef __attribute__((ext_vector_type(8))) short short8;     // 8 bf16
typedef __attribute__((ext_vector_type(4))) float floatx4;    // MFMA C/D
typedef unsigned int uint;

__device__ __forceinline__ unsigned short f2bf(float f) {
  unsigned int u = __float_as_uint(f);
  return (unsigned short)((u + 0x7fffu + ((u >> 16) & 1u)) >> 16);  // RNE
}

// exact insertion of t into ascending sorted-6 (keep smallest 6): 6 VALU ops
__device__ __forceinline__ uint med3u(uint a, uint b, uint c) {
  uint d;
  asm("v_med3_u32 %0, %1, %2, %3" : "=v"(d) : "v"(a), "v"(b), "v"(c));
  return d;
}
__device__ __forceinline__ void ins6(uint* a, uint t) {
  a[5] = med3u(a[4], a[5], t);
  a[4] = med3u(a[3], a[4], t);
  a[3] = med3u(a[2], a[3], t);
  a[2] = med3u(a[1], a[2], t);
  a[1] = med3u(a[0], a[1], t);
  a[0] = min(a[0], t);
}
__device__ __forceinline__ void ins12(uint* a, uint t) {
  a[11] = med3u(a[10], a[11], t);
  a[10] = med3u(a[9], a[10], t);
  a[9]  = med3u(a[8], a[9], t);
  a[8]  = med3u(a[7], a[8], t);
  a[7]  = med3u(a[6], a[7], t);
  a[6]  = med3u(a[5], a[6], t);
  a[5]  = med3u(a[4], a[5], t);
  a[4]  = med3u(a[3], a[4], t);
  a[3]  = med3u(a[2], a[3], t);
  a[2]  = med3u(a[1], a[2], t);
  a[1]  = med3u(a[0], a[1], t);
  a[0]  = min(a[0], t);
}

// fence-free cross-block handoff (CDNA4): relaxed agent-scope atomics bypass
// the per-XCD L2 (sc-bits) -> always coherent, NEVER invalidate caches.
// R7's __threadfence() (L2 wb/inv per call) was the 2.6x regression.
__device__ __forceinline__ void ag_store(uint* p, uint v) {
  __hip_atomic_store(p, v, __ATOMIC_RELAXED, __HIP_MEMORY_SCOPE_AGENT);
}
__device__ __forceinline__ uint ag_load(const uint* p) {
  return __hip_atomic_load(p, __ATOMIC_RELAXED, __HIP_MEMORY_SCOPE_AGENT);
}
__device__ __forceinline__ void ag_storef(float* p, float v) {
  __hip_atomic_store(p, v, __ATOMIC_RELAXED, __HIP_MEMORY_SCOPE_AGENT);
}
__device__ __forceinline__ float ag_loadf(const float* p) {
  return __hip_atomic_load(p, __ATOMIC_RELAXED, __HIP_MEMORY_SCOPE_AGENT);
}

// ---------------- K0: col-major swizzled bf16 records + tn + scaled tn256 ----------------
// Also zeroes the 251 sync counters (250 per-rb + 1 grid) each launch.
__global__ void tn_cast_kernel(const float* __restrict__ tf, float* __restrict__ tn,
                               float* __restrict__ tn256,
                               unsigned short* __restrict__ tfbx,
                               uint* __restrict__ cntp) {
  int gid = blockIdx.x * blockDim.x + threadIdx.x;
  if (gid < 251) cntp[gid] = 0;
  int w = gid >> 6;
  int lane = gid & 63;
  if (w >= TPAD) return;
  unsigned short* base = tfbx + (size_t)w * 128;
  int jj = lane >> 2;
  int soff = ((jj ^ (w & 7)) << 3) + (lane & 3) * 2;
  if (w < TT) {
    const float* p = tf + (size_t)w * FE;
    float a = p[lane];
    float b = p[lane + 64];
    float s = a * a + b * b;
#pragma unroll
    for (int off = 32; off > 0; off >>= 1) s += __shfl_xor(s, off);
    if (lane == 0) { tn[w] = s; tn256[w] = -0.5f * (s + 256.0f); }
    ushort2 o;
    o.x = f2bf(p[2 * lane]);
    o.y = f2bf(p[2 * lane + 1]);
    *reinterpret_cast<ushort2*>(base + soff) = o;
  } else {
    if (lane == 0) { tn[w] = 1e30f; tn256[w] = -1.5e38f; }  // pads never win
    ushort2 z; z.x = 0; z.y = 0;
    *reinterpret_cast<ushort2*>(base + soff) = z;
  }
}

// ---------------- K1: 80-row GEMM + top-6 + fused merge (fence-free last-arriver) ----------------
// Main body = R4's proven config (prefetch, (256,2), 66 us). pkall slices are
// written with relaxed agent atomics; vmcnt drains at __syncthreads (compiler
// emits s_waitcnt vmcnt(0) before s_barrier) order them before the arrival
// atomicAdd. The 4th arriver re-reads all 4 slices with agent loads (bypass,
// fresh) and runs the exact R4 merge arithmetic for its 80 rows.
union SmemK1 {
  unsigned short Bs[RPB * 128];   // 20480 B staged source rows
  uint pk[RPB][24];               // 7680 B epilogue overlay
  struct { uint kk[4][24]; float sv[4][24]; int sc[4][24]; } t;  // merge tail
};

__device__ __forceinline__ void mfma4_sel(
    short8 a0, short8 a1, short8 a2, short8 a3,
    short8 b0, short8 b1, short8 b2, short8 b3,
    float4 t4, uint ck, uint* kqh) {
  floatx4 acc = (floatx4){t4.x, t4.y, t4.z, t4.w};
  acc = __builtin_amdgcn_mfma_f32_16x16x32_bf16(a0, b0, acc, 0, 0, 0);
  acc = __builtin_amdgcn_mfma_f32_16x16x32_bf16(a1, b1, acc, 0, 0, 0);
  acc = __builtin_amdgcn_mfma_f32_16x16x32_bf16(a2, b2, acc, 0, 0, 0);
  acc = __builtin_amdgcn_mfma_f32_16x16x32_bf16(a3, b3, acc, 0, 0, 0);
#pragma unroll
  for (int r = 0; r < 4; ++r) {
    uint t = (__float_as_uint(acc[r]) & 0xFFFFE000u) | (ck + (uint)r);
    ins6(kqh, t);
  }
}

__global__ __launch_bounds__(256, 2) void topk_kernel(
    const float* __restrict__ sf, const float* __restrict__ tf,
    const unsigned short* __restrict__ tfbx,
    const float* __restrict__ tn256, const float* __restrict__ tn,
    const float* __restrict__ tp, uint* __restrict__ pkall,
    float* __restrict__ pred, uint* __restrict__ cnt) {
  __shared__ SmemK1 u;
  __shared__ int lastFlag;
  const int tid = threadIdx.x;
  const int lane = tid & 63;
  const int wv = tid >> 6;
  const int q = lane >> 4;
  const int m = lane & 15;
  const int rb = (int)blockIdx.x >> 2;
  const int cb = (int)blockIdx.x & 3;
  const int row0 = rb * RPB;          // exact: 250*80 = 20000
  const int cbase = cb * CBW;

  // one-time stage: 80 source rows -> Bs (bf16, swizzled)
#pragma unroll
  for (int t = 0; t < 5; ++t) {
    int c = tid + t * 256;
    int rr = c >> 4, jj = c & 15;
    const float* src = sf + (size_t)(row0 + rr) * FE + jj * 8;
    float4 f0 = *reinterpret_cast<const float4*>(src);
    float4 f1 = *reinterpret_cast<const float4*>(src + 4);
    union { unsigned short us[8]; uint4 v; } tt;
    tt.us[0] = f2bf(f0.x); tt.us[1] = f2bf(f0.y);
    tt.us[2] = f2bf(f0.z); tt.us[3] = f2bf(f0.w);
    tt.us[4] = f2bf(f1.x); tt.us[5] = f2bf(f1.y);
    tt.us[6] = f2bf(f1.z); tt.us[7] = f2bf(f1.w);
    *reinterpret_cast<uint4*>(u.Bs + rr * 128 + ((jj ^ (rr & 7)) << 3)) = tt.v;
  }

  uint kq[NH][6];
#pragma unroll
  for (int h = 0; h < NH; ++h)
#pragma unroll
    for (int k = 0; k < 6; ++k) kq[h][k] = 0xFFFFFFFFu;

  int rdB[4];
  int aoff[4];
  const int ax = m & 7;
#pragma unroll
  for (int ks = 0; ks < 4; ++ks) {
    int slot = (ks * 4 + q) ^ ax;
    rdB[ks] = m * 128 + (slot << 3);
    aoff[ks] = slot << 3;
  }
  const unsigned short* abase = tfbx + (size_t)(cbase + wv * 16 + m) * 128;
  const uint ck0 = (uint)(cbase + wv * 16 + q * 4);

  __syncthreads();

  // hoist B fragments (compiler manages residency; R5 proved this is fine)
  short8 bf[NH][4];
#pragma unroll
  for (int h = 0; h < NH; ++h) {
    const unsigned short* bb = u.Bs + h * 2048;
#pragma unroll
    for (int ks = 0; ks < 4; ++ks)
      bf[h][ks] = *reinterpret_cast<const short8*>(bb + rdB[ks]);
  }

  // main loop: A direct from global (L2), prefetched 1 strip ahead
  short8 a0 = *reinterpret_cast<const short8*>(abase + aoff[0]);
  short8 a1 = *reinterpret_cast<const short8*>(abase + aoff[1]);
  short8 a2 = *reinterpret_cast<const short8*>(abase + aoff[2]);
  short8 a3 = *reinterpret_cast<const short8*>(abase + aoff[3]);
  float4 t4 = *reinterpret_cast<const float4*>(tn256 + cbase + wv * 16 + q * 4);

  for (int s = 0; s < 27; ++s) {
    const int sn = (s < 26) ? s + 1 : 26;     // clamp: avoid OOB prefetch
    const unsigned short* apn = abase + (size_t)sn * 8192;
    short8 na0 = *reinterpret_cast<const short8*>(apn + aoff[0]);
    short8 na1 = *reinterpret_cast<const short8*>(apn + aoff[1]);
    short8 na2 = *reinterpret_cast<const short8*>(apn + aoff[2]);
    short8 na3 = *reinterpret_cast<const short8*>(apn + aoff[3]);
    float4 nt4 = *reinterpret_cast<const float4*>(
        tn256 + cbase + sn * 64 + wv * 16 + q * 4);
    const uint ck = ck0 + (uint)(s * 64);
#pragma unroll
    for (int h = 0; h < NH; ++h)
      mfma4_sel(a0, a1, a2, a3, bf[h][0], bf[h][1], bf[h][2], bf[h][3],
                t4, ck, kq[h]);
    a0 = na0; a1 = na1; a2 = na2; a3 = na3; t4 = nt4;
  }

  // merge across the 4 q-lanes via shfl butterfly (exact top-6 of 24)
#pragma unroll
  for (int h = 0; h < NH; ++h) {
#pragma unroll
    for (int st = 16; st <= 32; st <<= 1) {
      uint inc[6];
#pragma unroll
      for (int k = 0; k < 6; ++k) inc[k] = __shfl_xor(kq[h][k], st);
#pragma unroll
      for (int k = 0; k < 6; ++k) ins6(kq[h], inc[k]);
    }
  }
  __syncthreads();   // Bs dead; overlay epilogue
  if (q == 0) {
#pragma unroll
    for (int h = 0; h < NH; ++h)
#pragma unroll
      for (int k = 0; k < 6; ++k) u.pk[h * 16 + m][wv * 6 + k] = kq[h][k];
  }
  __syncthreads();

  // per row: exact top-12 of the 24 -> pkall[row][cb*12..] (agent stores)
  if (tid < RPB) {
    uint md[12];
#pragma unroll
    for (int k = 0; k < 12; ++k) md[k] = 0xFFFFFFFFu;
    for (int j = 0; j < 24; ++j) ins12(md, u.pk[tid][j]);
    uint* dst = pkall + (size_t)(row0 + tid) * 48 + cb * 12;
#pragma unroll
    for (int k = 0; k < 12; ++k) ag_store(dst + k, md[k]);
  }

  // ---- fence-free last-arriver handoff ----
  asm volatile("s_waitcnt vmcnt(0)" ::: "memory");  // per-wave store drain
  __syncthreads();
  if (tid == 0) {
    uint old = __hip_atomic_fetch_add(&cnt[rb], 1u, __ATOMIC_RELAXED,
                                      __HIP_MEMORY_SCOPE_AGENT);
    lastFlag = (old == 3u) ? 1 : 0;
  }
  __syncthreads();
  if (!lastFlag) return;

  // last arriver: merge 48 -> fp32 rescore top-24 -> top-6 -> pred (80 rows)
  for (int rr = wv; rr < RPB; rr += 4) {   // 20 rows per wave
    const int row = row0 + rr;
    uint k0 = 0xFFFFFFFFu;
    if (lane < 48) k0 = ag_load(pkall + (size_t)row * 48 + lane);
    int rk = 0;
    for (int j = 0; j < 48; ++j) {
      uint a = __shfl(k0, j);
      rk += (a < k0) ? 1 : 0;              // keys unique (distinct col bits)
    }
    if (lane < 48 && rk < 24) u.t.kk[wv][rk] = k0;  // compact top-24 by rank
    const int g = lane >> 2;
    const int c4 = lane & 3;
    const float* srow = sf + (size_t)row * FE;
    float4 sfc[8];
#pragma unroll
    for (int it = 0; it < 8; ++it)
      sfc[it] = *reinterpret_cast<const float4*>(srow + (it * 4 + c4) * 4);
#pragma unroll
    for (int p = 0; p < 2; ++p) {
      const int j = p * 16 + g;
      if (j < 24) {
        const int col = (int)(u.t.kk[wv][j] & 0x1FFFu);
        const float* trow = tf + (size_t)col * FE;
        float acc = 0.f;
#pragma unroll
        for (int it = 0; it < 8; ++it) {
          float4 bv = *reinterpret_cast<const float4*>(trow + (it * 4 + c4) * 4);
          float4 av = sfc[it];
          acc += av.x * bv.x + av.y * bv.y + av.z * bv.z + av.w * bv.w;
        }
        acc += __shfl_xor(acc, 1);
        acc += __shfl_xor(acc, 2);
        if (c4 == 0) {                     // rank j is a unique slot
          u.t.sv[wv][j] = tn[col] - 2.f * acc;
          u.t.sc[wv][j] = col;
        }
      }
    }
    if (lane == 0) {
      float sd[6]; int sp6[6];
#pragma unroll
      for (int k = 0; k < 6; ++k) { sd[k] = 1e30f; sp6[k] = 0; }
      for (int j = 0; j < 24; ++j) {
        float v = u.t.sv[wv][j];
        if (v < sd[5]) {
          sd[5] = v; sp6[5] = j;
#pragma unroll
          for (int k = 4; k >= 0; --k) {
            if (sd[k + 1] < sd[k]) {
              float tvv = sd[k]; sd[k] = sd[k + 1]; sd[k + 1] = tvv;
              int tii = sp6[k]; sp6[k] = sp6[k + 1]; sp6[k + 1] = tii;
            }
          }
        }
      }
      float wgt[6]; float wsum = 0.f;
#pragma unroll
      for (int k = 0; k < 6; ++k) { wgt[k] = __expf(sd[0] - sd[k]); wsum += wgt[k]; }
      float inv = 1.f / wsum;
      float px = 0.f, py = 0.f, pz = 0.f;
#pragma unroll
      for (int k = 0; k < 6; ++k) {
        float scv = wgt[k] * inv;
        const float* qq = tp + (size_t)u.t.sc[wv][sp6[k]] * 3;
        px += scv * qq[0]; py += scv * qq[1]; pz += scv * qq[2];
      }
      pred[row * 3 + 0] = px;      // normal store: next-kernel boundary coheres
      pred[row * 3 + 1] = py;
      pred[row * 3 + 2] = pz;
    }
  }
}

// ---------------- K2: Procrustes + fused dst (fence-free grid barrier) ----------------
// 313 blocks <= 512 resident slots at (256,2) -> barrier deadlock-free.
// qnorm handoff uses relaxed agent atomics (no cache ops); poll is a relaxed
// atomic load (R7's ACQUIRE poll invalidated L2 per iteration — the bug).
__global__ __launch_bounds__(256, 2) void proc_kernel(
    const int* __restrict__ colp, const float* __restrict__ pos,
    const float* __restrict__ pred, float* __restrict__ Rout,
    float* __restrict__ tout, float* __restrict__ qnorm,
    float* __restrict__ dout, uint* __restrict__ cnt2) {
  int t = blockIdx.x * blockDim.x + threadIdx.x;
  int i = t >> 2;
  int l = t & 3;
  const bool valid = (i < NS);
  const int ic = valid ? i : (NS - 1);     // clamp: uniform control flow
  int4 cia[2];
#pragma unroll
  for (int tt = 0; tt < 2; ++tt)
    cia[tt] = reinterpret_cast<const int4*>(colp + (size_t)ic * DEG + l * 8)[tt];
  const int* cidx = reinterpret_cast<const int*>(cia);

  double sp[3] = {0, 0, 0}, sq[3] = {0, 0, 0};
  double spq[3][3] = {{0, 0, 0}, {0, 0, 0}, {0, 0, 0}};
#pragma unroll
  for (int e = 0; e < 8; ++e) {
    int c = cidx[e];
    double p0 = pos[c * 3], p1 = pos[c * 3 + 1], p2 = pos[c * 3 + 2];
    double q0 = pred[c * 3], q1 = pred[c * 3 + 1], q2 = pred[c * 3 + 2];
    sp[0] += p0; sp[1] += p1; sp[2] += p2;
    sq[0] += q0; sq[1] += q1; sq[2] += q2;
    spq[0][0] += p0 * q0; spq[0][1] += p0 * q1; spq[0][2] += p0 * q2;
    spq[1][0] += p1 * q0; spq[1][1] += p1 * q1; spq[1][2] += p1 * q2;
    spq[2][0] += p2 * q0; spq[2][1] += p2 * q1; spq[2][2] += p2 * q2;
  }
#pragma unroll
  for (int mask = 1; mask <= 2; mask <<= 1) {
#pragma unroll
    for (int a = 0; a < 3; ++a) {
      sp[a] += __shfl_xor(sp[a], mask);
      sq[a] += __shfl_xor(sq[a], mask);
#pragma unroll
      for (int b = 0; b < 3; ++b) spq[a][b] += __shfl_xor(spq[a][b], mask);
    }
  }

  const double inv = 1.0 / 32.0;
  double A[3][3], sc[3], tcn[3];
  for (int a = 0; a < 3; ++a) {
    sc[a] = sp[a] * inv;
    tcn[a] = sq[a] * inv;
  }
  for (int a = 0; a < 3; ++a)
    for (int b = 0; b < 3; ++b) A[a][b] = spq[a][b] - sp[a] * sq[b] * inv;

  double S[3][3];
  for (int a = 0; a < 3; ++a)
    for (int b = 0; b < 3; ++b)
      S[a][b] = A[0][a] * A[0][b] + A[1][a] * A[1][b] + A[2][a] * A[2][b];
  double V[3][3] = {{1, 0, 0}, {0, 1, 0}, {0, 0, 1}};
  const int JP[3] = {0, 0, 1}, JQ[3] = {1, 2, 2};
  for (int sweep = 0; sweep < 6; ++sweep) {
    for (int r = 0; r < 3; ++r) {
      int p = JP[r], q = JQ[r];
      double apq = S[p][q];
      if (fabs(apq) < 1e-300) continue;
      double theta = (S[q][q] - S[p][p]) / (2.0 * apq);
      double t2 = copysign(1.0 / (fabs(theta) + sqrt(theta * theta + 1.0)), theta);
      double c = 1.0 / sqrt(t2 * t2 + 1.0);
      double s = t2 * c;
      double spp = S[p][p], sqq = S[q][q];
      S[p][p] = spp - t2 * apq;
      S[q][q] = sqq + t2 * apq;
      S[p][q] = 0.0; S[q][p] = 0.0;
      int k = 3 - p - q;
      double skp = S[k][p], skq = S[k][q];
      S[k][p] = S[p][k] = c * skp - s * skq;
      S[k][q] = S[q][k] = s * skp + c * skq;
      for (int mth = 0; mth < 3; ++mth) {
        double vp = V[mth][p], vq = V[mth][q];
        V[mth][p] = c * vp - s * vq;
        V[mth][q] = s * vp + c * vq;
      }
    }
  }
  double lam[3] = {S[0][0], S[1][1], S[2][2]};
  int i0 = 0, i1 = 1, i2 = 2, tmp;
  if (lam[i0] < lam[i1]) { tmp = i0; i0 = i1; i1 = tmp; }
  if (lam[i0] < lam[i2]) { tmp = i0; i0 = i2; i2 = tmp; }
  if (lam[i1] < lam[i2]) { tmp = i1; i1 = i2; i2 = tmp; }
  double v0[3] = {V[0][i0], V[1][i0], V[2][i0]};
  double v1[3] = {V[0][i1], V[1][i1], V[2][i1]};
  double v2[3] = {V[0][i2], V[1][i2], V[2][i2]};

  double Av0[3], Av1[3], Av2[3];
  for (int a = 0; a < 3; ++a) {
    Av0[a] = A[a][0] * v0[0] + A[a][1] * v0[1] + A[a][2] * v0[2];
    Av1[a] = A[a][0] * v1[0] + A[a][1] * v1[1] + A[a][2] * v1[2];
    Av2[a] = A[a][0] * v2[0] + A[a][1] * v2[1] + A[a][2] * v2[2];
  }
  double n0 = fmax(sqrt(Av0[0]*Av0[0] + Av0[1]*Av0[1] + Av0[2]*Av0[2]), 1e-300);
  double u0[3] = {Av0[0] / n0, Av0[1] / n0, Av0[2] / n0};
  double proj = u0[0]*Av1[0] + u0[1]*Av1[1] + u0[2]*Av1[2];
  double u1[3] = {Av1[0] - proj * u0[0], Av1[1] - proj * u0[1], Av1[2] - proj * u0[2]};
  double n1 = fmax(sqrt(u1[0]*u1[0] + u1[1]*u1[1] + u1[2]*u1[2]), 1e-300);
  u1[0] /= n1; u1[1] /= n1; u1[2] /= n1;
  double w[3] = {u0[1]*u1[2] - u0[2]*u1[1],
                 u0[2]*u1[0] - u0[0]*u1[2],
                 u0[0]*u1[1] - u0[1]*u1[0]};
  double dotw = Av2[0]*w[0] + Av2[1]*w[1] + Av2[2]*w[2];
  double sgn = (dotw < 0.0) ? -1.0 : 1.0;
  double detA = A[0][0]*(A[1][1]*A[2][2] - A[1][2]*A[2][1])
              - A[0][1]*(A[1][0]*A[2][2] - A[1][2]*A[2][0])
              + A[0][2]*(A[1][0]*A[2][1] - A[1][1]*A[2][0]);
  double d3 = ((detA < 0.0) ? -1.0 : 1.0) * sgn;

  double R[3][3];
  for (int a = 0; a < 3; ++a)
    for (int b = 0; b < 3; ++b)
      R[a][b] = u0[a]*v0[b] + u1[a]*v1[b] + d3 * w[a]*v2[b];

  if (valid && l == 0) {
    for (int a = 0; a < 3; ++a)
      for (int b = 0; b < 3; ++b) Rout[i * 9 + a * 3 + b] = (float)R[a][b];
    double tr_[3];
    for (int a = 0; a < 3; ++a) {
      tr_[a] = tcn[a] - (R[a][0]*sc[0] + R[a][1]*sc[1] + R[a][2]*sc[2]);
      tout[i * 3 + a] = (float)tr_[a];
    }
    double pxi = pos[i * 3], pyi = pos[i * 3 + 1], pzi = pos[i * 3 + 2];
    double r0 = R[0][0]*pxi + R[0][1]*pyi + R[0][2]*pzi + tr_[0] - pred[i * 3];
    double r1 = R[1][0]*pxi + R[1][1]*pyi + R[1][2]*pzi + tr_[1] - pred[i * 3 + 1];
    double r2 = R[2][0]*pxi + R[2][1]*pyi + R[2][2]*pzi + tr_[2] - pred[i * 3 + 2];
    ag_storef(qnorm + i, (float)(r0 * r0 + r1 * r1 + r2 * r2));
  }

  // ---- fence-free grid barrier ----
  asm volatile("s_waitcnt vmcnt(0)" ::: "memory");  // qnorm stores drained
  __syncthreads();
  if (threadIdx.x == 0) {
    __hip_atomic_fetch_add(cnt2, 1u, __ATOMIC_RELAXED, __HIP_MEMORY_SCOPE_AGENT);
    while (ag_load(cnt2) < (uint)PBLK) __builtin_amdgcn_s_sleep(8);
  }
  __syncthreads();

  // ---- fused dst phase: per-node residual mean (agent loads, cache-bypass) ----
  {
    float s = 0.f;
#pragma unroll
    for (int e = 0; e < 8; ++e) s += ag_loadf(qnorm + cidx[e]);
    s += __shfl_xor(s, 1);
    s += __shfl_xor(s, 2);
    if (valid && l == 0) dout[i] = s * (1.0f / 32.0f);
  }
}

extern "C" void kernel_launch(void* const* d_in, const int* in_sizes, int n_in,
                              void* d_out, int out_size, void* d_ws, size_t ws_size,
                              hipStream_t stream) {
  const float* sf  = (const float*)d_in[0];   // [N,128]
  const float* tf  = (const float*)d_in[1];   // [T,128]
  const float* tp  = (const float*)d_in[2];   // [T,3]
  const float* pos = (const float*)d_in[3];   // [N,3]
  const int*   ei  = (const int*)d_in[4];     // [2,E]
  float* out = (float*)d_out;                 // [N*9 | N*3 | N]
  char* ws = (char*)d_ws;
  // ws layout (~5.9 MB; qn aliases tfbx which is dead after topk):
  float*          tn    = (float*)(ws);                    // 27,648 B
  float*          tn256 = (float*)(ws + 28672);            // 27,648 B used
  uint*           cntp  = (uint*)(ws + 56320);             // 251 uints (spare)
  float*          pred  = (float*)(ws + 57344);            // 240,000 B
  uint*           pkall = (uint*)(ws + 297344);            // 20000*48*4 = 3,840,000 B
  unsigned short* tfbx  = (unsigned short*)(ws + 4137344); // 1,769,472 B
  float*          qn    = (float*)(ws + 4137344);          // alias (post-topk)
  const int* colp = ei + EDG;

  tn_cast_kernel<<<(TPAD * 64) / 256, 256, 0, stream>>>(tf, tn, tn256, tfbx, cntp);
  topk_kernel<<<(NS / RPB) * NCB, 256, 0, stream>>>(sf, tf, tfbx, tn256, tn, tp,
                                                    pkall, pred, cntp);
  proc_kernel<<<PBLK, 256, 0, stream>>>(colp, pos, pred, out, out + NS * 9, qn,
                                        out + NS * 12, cntp + 250);
}

// Round 9
// 201.710 us; speedup vs baseline: 2.6780x; 1.7570x over previous
//
#include <hip/hip_runtime.h>
#include <math.h>

#define NS 20000
#define TT 6890
#define TPAD 6912
#define FE 128
#define EDG 640000
#define DEG 32

#define RPB 80            // rows per block (5 rowsets) -> 250 row-blocks exact
#define NCB 4             // col-blocks
#define CBW 1728          // cols per col-block (27 x 64-col strips)
#define NH 5              // rowsets per block

typedef __attribute__((ext_vector_type(8))) short short8;     // 8 bf16
typedef __attribute__((ext_vector_type(4))) float floatx4;    // MFMA C/D
typedef unsigned int uint;

__device__ __forceinline__ unsigned short f2bf(float f) {
  unsigned int u = __float_as_uint(f);
  return (unsigned short)((u + 0x7fffu + ((u >> 16) & 1u)) >> 16);  // RNE
}

// exact insertion of t into ascending sorted-6 (keep smallest 6): 6 VALU ops
__device__ __forceinline__ uint med3u(uint a, uint b, uint c) {
  uint d;
  asm("v_med3_u32 %0, %1, %2, %3" : "=v"(d) : "v"(a), "v"(b), "v"(c));
  return d;
}
__device__ __forceinline__ void ins6(uint* a, uint t) {
  a[5] = med3u(a[4], a[5], t);
  a[4] = med3u(a[3], a[4], t);
  a[3] = med3u(a[2], a[3], t);
  a[2] = med3u(a[1], a[2], t);
  a[1] = med3u(a[0], a[1], t);
  a[0] = min(a[0], t);
}
__device__ __forceinline__ void ins12(uint* a, uint t) {
  a[11] = med3u(a[10], a[11], t);
  a[10] = med3u(a[9], a[10], t);
  a[9]  = med3u(a[8], a[9], t);
  a[8]  = med3u(a[7], a[8], t);
  a[7]  = med3u(a[6], a[7], t);
  a[6]  = med3u(a[5], a[6], t);
  a[5]  = med3u(a[4], a[5], t);
  a[4]  = med3u(a[3], a[4], t);
  a[3]  = med3u(a[2], a[3], t);
  a[2]  = med3u(a[1], a[2], t);
  a[1]  = med3u(a[0], a[1], t);
  a[0]  = min(a[0], t);
}

// ---------------- K0: col-major swizzled bf16 records + tn + scaled tn256 ----------------
// Col w: 256 B at tfbx + w*128 shorts; 16B chunk jj stored at slot jj^(w&7).
// tn256 stores -0.5*(||t||^2 + 256) so the MFMA accumulator IS the (scaled,
// negated) metric: acc = -0.5*met < 0 => raw-bit uint order == ascending-met.
__global__ void tn_cast_kernel(const float* __restrict__ tf, float* __restrict__ tn,
                               float* __restrict__ tn256,
                               unsigned short* __restrict__ tfbx) {
  int gid = blockIdx.x * blockDim.x + threadIdx.x;
  int w = gid >> 6;
  int lane = gid & 63;
  if (w >= TPAD) return;
  unsigned short* base = tfbx + (size_t)w * 128;
  int jj = lane >> 2;
  int soff = ((jj ^ (w & 7)) << 3) + (lane & 3) * 2;
  if (w < TT) {
    const float* p = tf + (size_t)w * FE;
    float a = p[lane];
    float b = p[lane + 64];
    float s = a * a + b * b;
#pragma unroll
    for (int off = 32; off > 0; off >>= 1) s += __shfl_xor(s, off);
    if (lane == 0) { tn[w] = s; tn256[w] = -0.5f * (s + 256.0f); }
    ushort2 o;
    o.x = f2bf(p[2 * lane]);
    o.y = f2bf(p[2 * lane + 1]);
    *reinterpret_cast<ushort2*>(base + soff) = o;
  } else {
    if (lane == 0) { tn[w] = 1e30f; tn256[w] = -1.5e38f; }  // pads never win
    ushort2 z; z.x = 0; z.y = 0;
    *reinterpret_cast<ushort2*>(base + soff) = z;
  }
}

// ---------------- K1: 80-row register-stationary GEMM + per-substream top-6 ----------------
// Best-measured config (R4, 66.4 us): B fragments hoisted via LDS once,
// A fragments direct from global (L2) software-pipelined one strip ahead,
// launch_bounds(256,2). Fusion of the merge stage was tested twice (R7/R8)
// and regresses 150-340 us: cross-block handoff costs either L2 wb/inv
// (threadfence) or uncoalesced coherent-point traffic (agent atomics).
union SmemK1 {
  unsigned short Bs[RPB * 128];   // 20480 B staged source rows
  uint pk[RPB][24];               // 7680 B epilogue overlay
};

__device__ __forceinline__ void mfma4_sel(
    short8 a0, short8 a1, short8 a2, short8 a3,
    short8 b0, short8 b1, short8 b2, short8 b3,
    float4 t4, uint ck, uint* kqh) {
  floatx4 acc = (floatx4){t4.x, t4.y, t4.z, t4.w};
  acc = __builtin_amdgcn_mfma_f32_16x16x32_bf16(a0, b0, acc, 0, 0, 0);
  acc = __builtin_amdgcn_mfma_f32_16x16x32_bf16(a1, b1, acc, 0, 0, 0);
  acc = __builtin_amdgcn_mfma_f32_16x16x32_bf16(a2, b2, acc, 0, 0, 0);
  acc = __builtin_amdgcn_mfma_f32_16x16x32_bf16(a3, b3, acc, 0, 0, 0);
#pragma unroll
  for (int r = 0; r < 4; ++r) {
    uint t = (__float_as_uint(acc[r]) & 0xFFFFE000u) | (ck + (uint)r);
    ins6(kqh, t);
  }
}

__global__ __launch_bounds__(256, 2) void topk_kernel(
    const float* __restrict__ sf, const unsigned short* __restrict__ tfbx,
    const float* __restrict__ tn256, uint* __restrict__ pkall) {
  __shared__ SmemK1 u;
  const int tid = threadIdx.x;
  const int lane = tid & 63;
  const int wv = tid >> 6;
  const int q = lane >> 4;
  const int m = lane & 15;
  const int rb = (int)blockIdx.x >> 2;
  const int cb = (int)blockIdx.x & 3;
  const int row0 = rb * RPB;          // exact: 250*80 = 20000
  const int cbase = cb * CBW;

  // one-time stage: 80 source rows -> Bs (bf16, swizzled)
#pragma unroll
  for (int t = 0; t < 5; ++t) {
    int c = tid + t * 256;
    int rr = c >> 4, jj = c & 15;
    const float* src = sf + (size_t)(row0 + rr) * FE + jj * 8;
    float4 f0 = *reinterpret_cast<const float4*>(src);
    float4 f1 = *reinterpret_cast<const float4*>(src + 4);
    union { unsigned short us[8]; uint4 v; } tt;
    tt.us[0] = f2bf(f0.x); tt.us[1] = f2bf(f0.y);
    tt.us[2] = f2bf(f0.z); tt.us[3] = f2bf(f0.w);
    tt.us[4] = f2bf(f1.x); tt.us[5] = f2bf(f1.y);
    tt.us[6] = f2bf(f1.z); tt.us[7] = f2bf(f1.w);
    *reinterpret_cast<uint4*>(u.Bs + rr * 128 + ((jj ^ (rr & 7)) << 3)) = tt.v;
  }

  uint kq[NH][6];
#pragma unroll
  for (int h = 0; h < NH; ++h)
#pragma unroll
    for (int k = 0; k < 6; ++k) kq[h][k] = 0xFFFFFFFFu;

  int rdB[4];
  int aoff[4];
  const int ax = m & 7;
#pragma unroll
  for (int ks = 0; ks < 4; ++ks) {
    int slot = (ks * 4 + q) ^ ax;
    rdB[ks] = m * 128 + (slot << 3);
    aoff[ks] = slot << 3;
  }
  const unsigned short* abase = tfbx + (size_t)(cbase + wv * 16 + m) * 128;
  const uint ck0 = (uint)(cbase + wv * 16 + q * 4);

  __syncthreads();

  // hoist ALL B fragments to registers (statically indexed)
  short8 bf[NH][4];
#pragma unroll
  for (int h = 0; h < NH; ++h) {
    const unsigned short* bb = u.Bs + h * 2048;
#pragma unroll
    for (int ks = 0; ks < 4; ++ks)
      bf[h][ks] = *reinterpret_cast<const short8*>(bb + rdB[ks]);
  }

  // main loop: no LDS, A direct from global (L2), prefetched 1 strip ahead
  short8 a0 = *reinterpret_cast<const short8*>(abase + aoff[0]);
  short8 a1 = *reinterpret_cast<const short8*>(abase + aoff[1]);
  short8 a2 = *reinterpret_cast<const short8*>(abase + aoff[2]);
  short8 a3 = *reinterpret_cast<const short8*>(abase + aoff[3]);
  float4 t4 = *reinterpret_cast<const float4*>(tn256 + cbase + wv * 16 + q * 4);

  for (int s = 0; s < 27; ++s) {
    const int sn = (s < 26) ? s + 1 : 26;     // clamp: avoid OOB prefetch
    const unsigned short* apn = abase + (size_t)sn * 8192;
    short8 na0 = *reinterpret_cast<const short8*>(apn + aoff[0]);
    short8 na1 = *reinterpret_cast<const short8*>(apn + aoff[1]);
    short8 na2 = *reinterpret_cast<const short8*>(apn + aoff[2]);
    short8 na3 = *reinterpret_cast<const short8*>(apn + aoff[3]);
    float4 nt4 = *reinterpret_cast<const float4*>(
        tn256 + cbase + sn * 64 + wv * 16 + q * 4);
    const uint ck = ck0 + (uint)(s * 64);
#pragma unroll
    for (int h = 0; h < NH; ++h)
      mfma4_sel(a0, a1, a2, a3, bf[h][0], bf[h][1], bf[h][2], bf[h][3],
                t4, ck, kq[h]);
    a0 = na0; a1 = na1; a2 = na2; a3 = na3; t4 = nt4;
  }

  // merge across the 4 q-lanes via shfl butterfly (exact top-6 of 24)
#pragma unroll
  for (int h = 0; h < NH; ++h) {
#pragma unroll
    for (int st = 16; st <= 32; st <<= 1) {
      uint inc[6];
#pragma unroll
      for (int k = 0; k < 6; ++k) inc[k] = __shfl_xor(kq[h][k], st);
#pragma unroll
      for (int k = 0; k < 6; ++k) ins6(kq[h], inc[k]);
    }
  }
  __syncthreads();   // Bs dead (all reads precede this barrier); overlay epilogue
  if (q == 0) {
#pragma unroll
    for (int h = 0; h < NH; ++h)
#pragma unroll
      for (int k = 0; k < 6; ++k) u.pk[h * 16 + m][wv * 6 + k] = kq[h][k];
  }
  __syncthreads();

  // per row: exact top-12 of the 24 -> pkall[row][cb*12..]
  if (tid < RPB) {
    uint md[12];
#pragma unroll
    for (int k = 0; k < 12; ++k) md[k] = 0xFFFFFFFFu;
    for (int j = 0; j < 24; ++j) ins12(md, u.pk[tid][j]);
    uint* dst = pkall + (size_t)(row0 + tid) * 48 + cb * 12;
#pragma unroll
    for (int k = 0; k < 12; ++k) dst[k] = md[k];
  }
}

// ---------------- K1b: merge 48 candidates/row, fp32 rescore top-24 only ----------------
// Rank-compact the 48 bf16 keys to the top-24 FIRST (LDS kk[wv][rank]), then
// fp32-rescore only those 24. Survivor set identical to rescoring all 48.
__global__ __launch_bounds__(256) void merge_kernel(
    const float* __restrict__ sf, const float* __restrict__ tf,
    const float* __restrict__ tn, const uint* __restrict__ pkall,
    const float* __restrict__ tp, float* __restrict__ pred) {
  __shared__ uint  kk[4][24];
  __shared__ float sv[4][24];
  __shared__ int   sc[4][24];
  const int lane = threadIdx.x & 63;
  const int wv = threadIdx.x >> 6;
  const int row = (int)blockIdx.x * 4 + wv;   // exact: 5000*4 = 20000
  uint k0 = 0xFFFFFFFFu;
  if (lane < 48) k0 = pkall[(size_t)row * 48 + lane];
  int r0 = 0;
  for (int j = 0; j < 48; ++j) {
    uint a = __shfl(k0, j);
    r0 += (a < k0) ? 1 : 0;                   // keys unique (distinct col bits)
  }
  if (lane < 48 && r0 < 24) kk[wv][r0] = k0;  // compact top-24 by rank
  __syncthreads();

  const int g = lane >> 2;                    // candidate slot within pass
  const int c4 = lane & 3;                    // chunk lane
  float4 sfc[8];
  const float* srow = sf + (size_t)row * FE;
#pragma unroll
  for (int it = 0; it < 8; ++it)
    sfc[it] = *reinterpret_cast<const float4*>(srow + (it * 4 + c4) * 4);
#pragma unroll
  for (int p = 0; p < 2; ++p) {
    const int j = p * 16 + g;
    if (j < 24) {
      const int col = (int)(kk[wv][j] & 0x1FFFu);
      const float* trow = tf + (size_t)col * FE;
      float acc = 0.f;
#pragma unroll
      for (int it = 0; it < 8; ++it) {
        float4 bv = *reinterpret_cast<const float4*>(trow + (it * 4 + c4) * 4);
        float4 av = sfc[it];
        acc += av.x * bv.x + av.y * bv.y + av.z * bv.z + av.w * bv.w;
      }
      acc += __shfl_xor(acc, 1);
      acc += __shfl_xor(acc, 2);
      if (c4 == 0) {                          // j IS the rank -> unique slot
        sv[wv][j] = tn[col] - 2.f * acc;
        sc[wv][j] = col;
      }
    }
  }
  __syncthreads();
  if (lane == 0) {
    float sd[6]; int sp6[6];
#pragma unroll
    for (int k = 0; k < 6; ++k) { sd[k] = 1e30f; sp6[k] = 0; }
    for (int j = 0; j < 24; ++j) {
      float v = sv[wv][j];
      if (v < sd[5]) {
        sd[5] = v; sp6[5] = j;
#pragma unroll
        for (int k = 4; k >= 0; --k) {
          if (sd[k + 1] < sd[k]) {
            float tvv = sd[k]; sd[k] = sd[k + 1]; sd[k + 1] = tvv;
            int tii = sp6[k]; sp6[k] = sp6[k + 1]; sp6[k + 1] = tii;
          }
        }
      }
    }
    float wgt[6]; float wsum = 0.f;
#pragma unroll
    for (int k = 0; k < 6; ++k) { wgt[k] = __expf(sd[0] - sd[k]); wsum += wgt[k]; }
    float inv = 1.f / wsum;
    float px = 0.f, py = 0.f, pz = 0.f;
#pragma unroll
    for (int k = 0; k < 6; ++k) {
      float scv = wgt[k] * inv;
      const float* qq = tp + (size_t)sc[wv][sp6[k]] * 3;
      px += scv * qq[0]; py += scv * qq[1]; pz += scv * qq[2];
    }
    pred[row * 3 + 0] = px;
    pred[row * 3 + 1] = py;
    pred[row * 3 + 2] = pz;
  }
}

// ---------------- K2: per-node Procrustes (3x3 SVD, fp64 Jacobi) ----------------
// 4 lanes per node; butterfly-reduce the 15 fp64 sums over lanes {xor 1,2};
// all 4 lanes redundantly run the chain-bound SVD; lane 0 writes.
__global__ __launch_bounds__(256) void proc_kernel(
    const int* __restrict__ colp, const float* __restrict__ pos,
    const float* __restrict__ pred, float* __restrict__ Rout,
    float* __restrict__ tout, float* __restrict__ qnorm) {
  int t = blockIdx.x * blockDim.x + threadIdx.x;
  int i = t >> 2;
  int l = t & 3;
  if (i >= NS) return;
  int4 cia[2];
#pragma unroll
  for (int tt = 0; tt < 2; ++tt)
    cia[tt] = reinterpret_cast<const int4*>(colp + (size_t)i * DEG + l * 8)[tt];
  const int* cidx = reinterpret_cast<const int*>(cia);

  double sp[3] = {0, 0, 0}, sq[3] = {0, 0, 0};
  double spq[3][3] = {{0, 0, 0}, {0, 0, 0}, {0, 0, 0}};
#pragma unroll
  for (int e = 0; e < 8; ++e) {
    int c = cidx[e];
    double p0 = pos[c * 3], p1 = pos[c * 3 + 1], p2 = pos[c * 3 + 2];
    double q0 = pred[c * 3], q1 = pred[c * 3 + 1], q2 = pred[c * 3 + 2];
    sp[0] += p0; sp[1] += p1; sp[2] += p2;
    sq[0] += q0; sq[1] += q1; sq[2] += q2;
    spq[0][0] += p0 * q0; spq[0][1] += p0 * q1; spq[0][2] += p0 * q2;
    spq[1][0] += p1 * q0; spq[1][1] += p1 * q1; spq[1][2] += p1 * q2;
    spq[2][0] += p2 * q0; spq[2][1] += p2 * q1; spq[2][2] += p2 * q2;
  }
  // butterfly reduce over the 4-lane group (xor 1, 2)
#pragma unroll
  for (int mask = 1; mask <= 2; mask <<= 1) {
#pragma unroll
    for (int a = 0; a < 3; ++a) {
      sp[a] += __shfl_xor(sp[a], mask);
      sq[a] += __shfl_xor(sq[a], mask);
#pragma unroll
      for (int b = 0; b < 3; ++b) spq[a][b] += __shfl_xor(spq[a][b], mask);
    }
  }

  const double inv = 1.0 / 32.0;
  double A[3][3], sc[3], tcn[3];
  for (int a = 0; a < 3; ++a) {
    sc[a] = sp[a] * inv;
    tcn[a] = sq[a] * inv;
  }
  for (int a = 0; a < 3; ++a)
    for (int b = 0; b < 3; ++b) A[a][b] = spq[a][b] - sp[a] * sq[b] * inv;

  double S[3][3];
  for (int a = 0; a < 3; ++a)
    for (int b = 0; b < 3; ++b)
      S[a][b] = A[0][a] * A[0][b] + A[1][a] * A[1][b] + A[2][a] * A[2][b];
  double V[3][3] = {{1, 0, 0}, {0, 1, 0}, {0, 0, 1}};
  const int JP[3] = {0, 0, 1}, JQ[3] = {1, 2, 2};
  for (int sweep = 0; sweep < 6; ++sweep) {
    for (int r = 0; r < 3; ++r) {
      int p = JP[r], q = JQ[r];
      double apq = S[p][q];
      if (fabs(apq) < 1e-300) continue;
      double theta = (S[q][q] - S[p][p]) / (2.0 * apq);
      double t2 = copysign(1.0 / (fabs(theta) + sqrt(theta * theta + 1.0)), theta);
      double c = 1.0 / sqrt(t2 * t2 + 1.0);
      double s = t2 * c;
      double spp = S[p][p], sqq = S[q][q];
      S[p][p] = spp - t2 * apq;
      S[q][q] = sqq + t2 * apq;
      S[p][q] = 0.0; S[q][p] = 0.0;
      int k = 3 - p - q;
      double skp = S[k][p], skq = S[k][q];
      S[k][p] = S[p][k] = c * skp - s * skq;
      S[k][q] = S[q][k] = s * skp + c * skq;
      for (int mth = 0; mth < 3; ++mth) {
        double vp = V[mth][p], vq = V[mth][q];
        V[mth][p] = c * vp - s * vq;
        V[mth][q] = s * vp + c * vq;
      }
    }
  }
  double lam[3] = {S[0][0], S[1][1], S[2][2]};
  int i0 = 0, i1 = 1, i2 = 2, tmp;
  if (lam[i0] < lam[i1]) { tmp = i0; i0 = i1; i1 = tmp; }
  if (lam[i0] < lam[i2]) { tmp = i0; i0 = i2; i2 = tmp; }
  if (lam[i1] < lam[i2]) { tmp = i1; i1 = i2; i2 = tmp; }
  double v0[3] = {V[0][i0], V[1][i0], V[2][i0]};
  double v1[3] = {V[0][i1], V[1][i1], V[2][i1]};
  double v2[3] = {V[0][i2], V[1][i2], V[2][i2]};

  double Av0[3], Av1[3], Av2[3];
  for (int a = 0; a < 3; ++a) {
    Av0[a] = A[a][0] * v0[0] + A[a][1] * v0[1] + A[a][2] * v0[2];
    Av1[a] = A[a][0] * v1[0] + A[a][1] * v1[1] + A[a][2] * v1[2];
    Av2[a] = A[a][0] * v2[0] + A[a][1] * v2[1] + A[a][2] * v2[2];
  }
  double n0 = fmax(sqrt(Av0[0]*Av0[0] + Av0[1]*Av0[1] + Av0[2]*Av0[2]), 1e-300);
  double u0[3] = {Av0[0] / n0, Av0[1] / n0, Av0[2] / n0};
  double proj = u0[0]*Av1[0] + u0[1]*Av1[1] + u0[2]*Av1[2];
  double u1[3] = {Av1[0] - proj * u0[0], Av1[1] - proj * u0[1], Av1[2] - proj * u0[2]};
  double n1 = fmax(sqrt(u1[0]*u1[0] + u1[1]*u1[1] + u1[2]*u1[2]), 1e-300);
  u1[0] /= n1; u1[1] /= n1; u1[2] /= n1;
  double w[3] = {u0[1]*u1[2] - u0[2]*u1[1],
                 u0[2]*u1[0] - u0[0]*u1[2],
                 u0[0]*u1[1] - u0[1]*u1[0]};
  double dotw = Av2[0]*w[0] + Av2[1]*w[1] + Av2[2]*w[2];
  double sgn = (dotw < 0.0) ? -1.0 : 1.0;
  double detA = A[0][0]*(A[1][1]*A[2][2] - A[1][2]*A[2][1])
              - A[0][1]*(A[1][0]*A[2][2] - A[1][2]*A[2][0])
              + A[0][2]*(A[1][0]*A[2][1] - A[1][1]*A[2][0]);
  double d3 = ((detA < 0.0) ? -1.0 : 1.0) * sgn;

  double R[3][3];
  for (int a = 0; a < 3; ++a)
    for (int b = 0; b < 3; ++b)
      R[a][b] = u0[a]*v0[b] + u1[a]*v1[b] + d3 * w[a]*v2[b];

  if (l == 0) {
    for (int a = 0; a < 3; ++a)
      for (int b = 0; b < 3; ++b) Rout[i * 9 + a * 3 + b] = (float)R[a][b];
    double tr_[3];
    for (int a = 0; a < 3; ++a) {
      tr_[a] = tcn[a] - (R[a][0]*sc[0] + R[a][1]*sc[1] + R[a][2]*sc[2]);
      tout[i * 3 + a] = (float)tr_[a];
    }
    double pxi = pos[i * 3], pyi = pos[i * 3 + 1], pzi = pos[i * 3 + 2];
    double r0 = R[0][0]*pxi + R[0][1]*pyi + R[0][2]*pzi + tr_[0] - pred[i * 3];
    double r1 = R[1][0]*pxi + R[1][1]*pyi + R[1][2]*pzi + tr_[1] - pred[i * 3 + 1];
    double r2 = R[2][0]*pxi + R[2][1]*pyi + R[2][2]*pzi + tr_[2] - pred[i * 3 + 2];
    qnorm[i] = (float)(r0 * r0 + r1 * r1 + r2 * r2);
  }
}

// ---------------- K3: per-node residual mean over neighbors ----------------
// 4 lanes/node (each gathers 8, butterfly xor 1,2) -> 1252 waves.
__global__ __launch_bounds__(256) void dst_kernel(
    const int* __restrict__ colp, const float* __restrict__ qn,
    float* __restrict__ dout) {
  int t = blockIdx.x * blockDim.x + threadIdx.x;
  int i = t >> 2;
  int l = t & 3;
  if (i >= NS) return;
  int4 cia[2];
#pragma unroll
  for (int tt = 0; tt < 2; ++tt)
    cia[tt] = reinterpret_cast<const int4*>(colp + (size_t)i * DEG + l * 8)[tt];
  const int* cidx = reinterpret_cast<const int*>(cia);
  float s = 0.f;
#pragma unroll
  for (int e = 0; e < 8; ++e) s += qn[cidx[e]];
  s += __shfl_xor(s, 1);
  s += __shfl_xor(s, 2);
  if (l == 0) dout[i] = s * (1.0f / 32.0f);
}

extern "C" void kernel_launch(void* const* d_in, const int* in_sizes, int n_in,
                              void* d_out, int out_size, void* d_ws, size_t ws_size,
                              hipStream_t stream) {
  const float* sf  = (const float*)d_in[0];   // [N,128]
  const float* tf  = (const float*)d_in[1];   // [T,128]
  const float* tp  = (const float*)d_in[2];   // [T,3]
  const float* pos = (const float*)d_in[3];   // [N,3]
  const int*   ei  = (const int*)d_in[4];     // [2,E]
  float* out = (float*)d_out;                 // [N*9 | N*3 | N]
  char* ws = (char*)d_ws;
  // ws layout (~5.9 MB; qn aliases tfbx which is dead after topk):
  float*          tn    = (float*)(ws);                    // 27,648 B
  float*          tn256 = (float*)(ws + 28672);            // 27,648 B
  float*          pred  = (float*)(ws + 57344);            // 240,000 B
  uint*           pkall = (uint*)(ws + 297344);            // 20000*48*4 = 3,840,000 B
  unsigned short* tfbx  = (unsigned short*)(ws + 4137344); // 1,769,472 B
  float*          qn    = (float*)(ws + 4137344);          // alias (post-topk)
  const int* colp = ei + EDG;

  tn_cast_kernel<<<(TPAD * 64) / 256, 256, 0, stream>>>(tf, tn, tn256, tfbx);
  topk_kernel<<<(NS / RPB) * NCB, 256, 0, stream>>>(sf, tfbx, tn256, pkall);
  merge_kernel<<<NS / 4, 256, 0, stream>>>(sf, tf, tn, pkall, tp, pred);
  proc_kernel<<<(NS * 4 + 255) / 256, 256, 0, stream>>>(colp, pos, pred, out,
                                                        out + NS * 9, qn);
  dst_kernel<<<(NS * 4 + 255) / 256, 256, 0, stream>>>(colp, qn, out + NS * 12);
}

// Round 10
// 181.891 us; speedup vs baseline: 2.9697x; 1.1090x over previous
//
#include <hip/hip_runtime.h>
#include <math.h>

#define NS 20000
#define TT 6890
#define TPAD 6912
#define FE 128
#define EDG 640000
#define DEG 32

#define RPB 80            // rows per block (5 rowsets) -> 250 row-blocks exact
#define NCB 2             // col-blocks (R10: 4->2; 500 blocks = ONE resident generation)
#define CBW 3456          // cols per col-block (54 x 64-col strips)
#define NSTR 54           // strips per col-block
#define NH 5              // rowsets per block

typedef __attribute__((ext_vector_type(8))) short short8;     // 8 bf16
typedef __attribute__((ext_vector_type(4))) float floatx4;    // MFMA C/D
typedef unsigned int uint;

__device__ __forceinline__ unsigned short f2bf(float f) {
  unsigned int u = __float_as_uint(f);
  return (unsigned short)((u + 0x7fffu + ((u >> 16) & 1u)) >> 16);  // RNE
}

// exact insertion of t into ascending sorted-6 (keep smallest 6): 6 VALU ops
__device__ __forceinline__ uint med3u(uint a, uint b, uint c) {
  uint d;
  asm("v_med3_u32 %0, %1, %2, %3" : "=v"(d) : "v"(a), "v"(b), "v"(c));
  return d;
}
__device__ __forceinline__ void ins6(uint* a, uint t) {
  a[5] = med3u(a[4], a[5], t);
  a[4] = med3u(a[3], a[4], t);
  a[3] = med3u(a[2], a[3], t);
  a[2] = med3u(a[1], a[2], t);
  a[1] = med3u(a[0], a[1], t);
  a[0] = min(a[0], t);
}
__device__ __forceinline__ void ins12(uint* a, uint t) {
  a[11] = med3u(a[10], a[11], t);
  a[10] = med3u(a[9], a[10], t);
  a[9]  = med3u(a[8], a[9], t);
  a[8]  = med3u(a[7], a[8], t);
  a[7]  = med3u(a[6], a[7], t);
  a[6]  = med3u(a[5], a[6], t);
  a[5]  = med3u(a[4], a[5], t);
  a[4]  = med3u(a[3], a[4], t);
  a[3]  = med3u(a[2], a[3], t);
  a[2]  = med3u(a[1], a[2], t);
  a[1]  = med3u(a[0], a[1], t);
  a[0]  = min(a[0], t);
}

// ---------------- K0: col-major swizzled bf16 records + tn + scaled tn256 ----------------
// Col w: 256 B at tfbx + w*128 shorts; 16B chunk jj stored at slot jj^(w&7).
// tn256 stores -0.5*(||t||^2 + 256) so the MFMA accumulator IS the (scaled,
// negated) metric: acc = -0.5*met < 0 => raw-bit uint order == ascending-met.
__global__ void tn_cast_kernel(const float* __restrict__ tf, float* __restrict__ tn,
                               float* __restrict__ tn256,
                               unsigned short* __restrict__ tfbx) {
  int gid = blockIdx.x * blockDim.x + threadIdx.x;
  int w = gid >> 6;
  int lane = gid & 63;
  if (w >= TPAD) return;
  unsigned short* base = tfbx + (size_t)w * 128;
  int jj = lane >> 2;
  int soff = ((jj ^ (w & 7)) << 3) + (lane & 3) * 2;
  if (w < TT) {
    const float* p = tf + (size_t)w * FE;
    float a = p[lane];
    float b = p[lane + 64];
    float s = a * a + b * b;
#pragma unroll
    for (int off = 32; off > 0; off >>= 1) s += __shfl_xor(s, off);
    if (lane == 0) { tn[w] = s; tn256[w] = -0.5f * (s + 256.0f); }
    ushort2 o;
    o.x = f2bf(p[2 * lane]);
    o.y = f2bf(p[2 * lane + 1]);
    *reinterpret_cast<ushort2*>(base + soff) = o;
  } else {
    if (lane == 0) { tn[w] = 1e30f; tn256[w] = -1.5e38f; }  // pads never win
    ushort2 z; z.x = 0; z.y = 0;
    *reinterpret_cast<ushort2*>(base + soff) = z;
  }
}

// ---------------- K1: 80-row register-stationary GEMM + per-substream top-6 ----------------
// R4 schedule (prefetch, (256,2)) — measured floor for this structure.
// R10: NCB=2 -> 500 blocks, all co-resident (one generation): per-block
// staging/prologue/epilogue paid once instead of twice machine-wide, pkall
// halves to 24/row. Per-cb selection logic identical (top-12 of the 24
// wv-candidates per row); ck col field still fits 13 bits (max 6911).
union SmemK1 {
  unsigned short Bs[RPB * 128];   // 20480 B staged source rows
  uint pk[RPB][24];               // 7680 B epilogue overlay
};

__device__ __forceinline__ void mfma4_sel(
    short8 a0, short8 a1, short8 a2, short8 a3,
    short8 b0, short8 b1, short8 b2, short8 b3,
    float4 t4, uint ck, uint* kqh) {
  floatx4 acc = (floatx4){t4.x, t4.y, t4.z, t4.w};
  acc = __builtin_amdgcn_mfma_f32_16x16x32_bf16(a0, b0, acc, 0, 0, 0);
  acc = __builtin_amdgcn_mfma_f32_16x16x32_bf16(a1, b1, acc, 0, 0, 0);
  acc = __builtin_amdgcn_mfma_f32_16x16x32_bf16(a2, b2, acc, 0, 0, 0);
  acc = __builtin_amdgcn_mfma_f32_16x16x32_bf16(a3, b3, acc, 0, 0, 0);
#pragma unroll
  for (int r = 0; r < 4; ++r) {
    uint t = (__float_as_uint(acc[r]) & 0xFFFFE000u) | (ck + (uint)r);
    ins6(kqh, t);
  }
}

__global__ __launch_bounds__(256, 2) void topk_kernel(
    const float* __restrict__ sf, const unsigned short* __restrict__ tfbx,
    const float* __restrict__ tn256, uint* __restrict__ pkall) {
  __shared__ SmemK1 u;
  const int tid = threadIdx.x;
  const int lane = tid & 63;
  const int wv = tid >> 6;
  const int q = lane >> 4;
  const int m = lane & 15;
  const int rb = (int)blockIdx.x >> 1;
  const int cb = (int)blockIdx.x & 1;
  const int row0 = rb * RPB;          // exact: 250*80 = 20000
  const int cbase = cb * CBW;

  // one-time stage: 80 source rows -> Bs (bf16, swizzled)
#pragma unroll
  for (int t = 0; t < 5; ++t) {
    int c = tid + t * 256;
    int rr = c >> 4, jj = c & 15;
    const float* src = sf + (size_t)(row0 + rr) * FE + jj * 8;
    float4 f0 = *reinterpret_cast<const float4*>(src);
    float4 f1 = *reinterpret_cast<const float4*>(src + 4);
    union { unsigned short us[8]; uint4 v; } tt;
    tt.us[0] = f2bf(f0.x); tt.us[1] = f2bf(f0.y);
    tt.us[2] = f2bf(f0.z); tt.us[3] = f2bf(f0.w);
    tt.us[4] = f2bf(f1.x); tt.us[5] = f2bf(f1.y);
    tt.us[6] = f2bf(f1.z); tt.us[7] = f2bf(f1.w);
    *reinterpret_cast<uint4*>(u.Bs + rr * 128 + ((jj ^ (rr & 7)) << 3)) = tt.v;
  }

  uint kq[NH][6];
#pragma unroll
  for (int h = 0; h < NH; ++h)
#pragma unroll
    for (int k = 0; k < 6; ++k) kq[h][k] = 0xFFFFFFFFu;

  int rdB[4];
  int aoff[4];
  const int ax = m & 7;
#pragma unroll
  for (int ks = 0; ks < 4; ++ks) {
    int slot = (ks * 4 + q) ^ ax;
    rdB[ks] = m * 128 + (slot << 3);
    aoff[ks] = slot << 3;
  }
  const unsigned short* abase = tfbx + (size_t)(cbase + wv * 16 + m) * 128;
  const uint ck0 = (uint)(cbase + wv * 16 + q * 4);

  __syncthreads();

  // hoist ALL B fragments to registers (statically indexed)
  short8 bf[NH][4];
#pragma unroll
  for (int h = 0; h < NH; ++h) {
    const unsigned short* bb = u.Bs + h * 2048;
#pragma unroll
    for (int ks = 0; ks < 4; ++ks)
      bf[h][ks] = *reinterpret_cast<const short8*>(bb + rdB[ks]);
  }

  // main loop: A direct from global (L2), prefetched 1 strip ahead
  short8 a0 = *reinterpret_cast<const short8*>(abase + aoff[0]);
  short8 a1 = *reinterpret_cast<const short8*>(abase + aoff[1]);
  short8 a2 = *reinterpret_cast<const short8*>(abase + aoff[2]);
  short8 a3 = *reinterpret_cast<const short8*>(abase + aoff[3]);
  float4 t4 = *reinterpret_cast<const float4*>(tn256 + cbase + wv * 16 + q * 4);

  for (int s = 0; s < NSTR; ++s) {
    const int sn = (s < NSTR - 1) ? s + 1 : NSTR - 1;  // clamp: no OOB prefetch
    const unsigned short* apn = abase + (size_t)sn * 8192;
    short8 na0 = *reinterpret_cast<const short8*>(apn + aoff[0]);
    short8 na1 = *reinterpret_cast<const short8*>(apn + aoff[1]);
    short8 na2 = *reinterpret_cast<const short8*>(apn + aoff[2]);
    short8 na3 = *reinterpret_cast<const short8*>(apn + aoff[3]);
    float4 nt4 = *reinterpret_cast<const float4*>(
        tn256 + cbase + sn * 64 + wv * 16 + q * 4);
    const uint ck = ck0 + (uint)(s * 64);
#pragma unroll
    for (int h = 0; h < NH; ++h)
      mfma4_sel(a0, a1, a2, a3, bf[h][0], bf[h][1], bf[h][2], bf[h][3],
                t4, ck, kq[h]);
    a0 = na0; a1 = na1; a2 = na2; a3 = na3; t4 = nt4;
  }

  // merge across the 4 q-lanes via shfl butterfly (exact top-6 of 24)
#pragma unroll
  for (int h = 0; h < NH; ++h) {
#pragma unroll
    for (int st = 16; st <= 32; st <<= 1) {
      uint inc[6];
#pragma unroll
      for (int k = 0; k < 6; ++k) inc[k] = __shfl_xor(kq[h][k], st);
#pragma unroll
      for (int k = 0; k < 6; ++k) ins6(kq[h], inc[k]);
    }
  }
  __syncthreads();   // Bs dead (all reads precede this barrier); overlay epilogue
  if (q == 0) {
#pragma unroll
    for (int h = 0; h < NH; ++h)
#pragma unroll
      for (int k = 0; k < 6; ++k) u.pk[h * 16 + m][wv * 6 + k] = kq[h][k];
  }
  __syncthreads();

  // per row: exact top-12 of the 24 -> pkall[row][cb*12..]  (stride now 24)
  if (tid < RPB) {
    uint md[12];
#pragma unroll
    for (int k = 0; k < 12; ++k) md[k] = 0xFFFFFFFFu;
    for (int j = 0; j < 24; ++j) ins12(md, u.pk[tid][j]);
    uint* dst = pkall + (size_t)(row0 + tid) * 24 + cb * 12;
#pragma unroll
    for (int k = 0; k < 12; ++k) dst[k] = md[k];
  }
}

// ---------------- K1b: merge 24 candidates/row, fp32 rescore, top-6, pred ----------------
// R10: with NCB=2 there are only 24 candidates/row (per-cb bf16-top-12 x 2)
// -> the 48-key rank-compaction pass is deleted; ALL 24 are fp32-rescored
// (strictly safer selection than the old bf16-top-24-of-48 cut).
__global__ __launch_bounds__(256) void merge_kernel(
    const float* __restrict__ sf, const float* __restrict__ tf,
    const float* __restrict__ tn, const uint* __restrict__ pkall,
    const float* __restrict__ tp, float* __restrict__ pred) {
  __shared__ uint  kk[4][24];
  __shared__ float sv[4][24];
  __shared__ int   sc[4][24];
  const int lane = threadIdx.x & 63;
  const int wv = threadIdx.x >> 6;
  const int row = (int)blockIdx.x * 4 + wv;   // exact: 5000*4 = 20000
  if (lane < 24) kk[wv][lane] = pkall[(size_t)row * 24 + lane];
  __syncthreads();

  const int g = lane >> 2;                    // candidate slot within pass
  const int c4 = lane & 3;                    // chunk lane
  float4 sfc[8];
  const float* srow = sf + (size_t)row * FE;
#pragma unroll
  for (int it = 0; it < 8; ++it)
    sfc[it] = *reinterpret_cast<const float4*>(srow + (it * 4 + c4) * 4);
#pragma unroll
  for (int p = 0; p < 2; ++p) {
    const int j = p * 16 + g;
    if (j < 24) {
      const int col = (int)(kk[wv][j] & 0x1FFFu);
      const float* trow = tf + (size_t)col * FE;
      float acc = 0.f;
#pragma unroll
      for (int it = 0; it < 8; ++it) {
        float4 bv = *reinterpret_cast<const float4*>(trow + (it * 4 + c4) * 4);
        float4 av = sfc[it];
        acc += av.x * bv.x + av.y * bv.y + av.z * bv.z + av.w * bv.w;
      }
      acc += __shfl_xor(acc, 1);
      acc += __shfl_xor(acc, 2);
      if (c4 == 0) {                          // slot j unique per candidate
        sv[wv][j] = tn[col] - 2.f * acc;
        sc[wv][j] = col;
      }
    }
  }
  __syncthreads();
  if (lane == 0) {
    float sd[6]; int sp6[6];
#pragma unroll
    for (int k = 0; k < 6; ++k) { sd[k] = 1e30f; sp6[k] = 0; }
    for (int j = 0; j < 24; ++j) {
      float v = sv[wv][j];
      if (v < sd[5]) {
        sd[5] = v; sp6[5] = j;
#pragma unroll
        for (int k = 4; k >= 0; --k) {
          if (sd[k + 1] < sd[k]) {
            float tvv = sd[k]; sd[k] = sd[k + 1]; sd[k + 1] = tvv;
            int tii = sp6[k]; sp6[k] = sp6[k + 1]; sp6[k + 1] = tii;
          }
        }
      }
    }
    float wgt[6]; float wsum = 0.f;
#pragma unroll
    for (int k = 0; k < 6; ++k) { wgt[k] = __expf(sd[0] - sd[k]); wsum += wgt[k]; }
    float inv = 1.f / wsum;
    float px = 0.f, py = 0.f, pz = 0.f;
#pragma unroll
    for (int k = 0; k < 6; ++k) {
      float scv = wgt[k] * inv;
      const float* qq = tp + (size_t)sc[wv][sp6[k]] * 3;
      px += scv * qq[0]; py += scv * qq[1]; pz += scv * qq[2];
    }
    pred[row * 3 + 0] = px;
    pred[row * 3 + 1] = py;
    pred[row * 3 + 2] = pz;
  }
}

// ---------------- K2: per-node Procrustes (3x3 SVD, fp64 Jacobi) ----------------
// 4 lanes per node; butterfly-reduce the 15 fp64 sums over lanes {xor 1,2};
// all 4 lanes redundantly run the chain-bound SVD; lane 0 writes.
__global__ __launch_bounds__(256) void proc_kernel(
    const int* __restrict__ colp, const float* __restrict__ pos,
    const float* __restrict__ pred, float* __restrict__ Rout,
    float* __restrict__ tout, float* __restrict__ qnorm) {
  int t = blockIdx.x * blockDim.x + threadIdx.x;
  int i = t >> 2;
  int l = t & 3;
  if (i >= NS) return;
  int4 cia[2];
#pragma unroll
  for (int tt = 0; tt < 2; ++tt)
    cia[tt] = reinterpret_cast<const int4*>(colp + (size_t)i * DEG + l * 8)[tt];
  const int* cidx = reinterpret_cast<const int*>(cia);

  double sp[3] = {0, 0, 0}, sq[3] = {0, 0, 0};
  double spq[3][3] = {{0, 0, 0}, {0, 0, 0}, {0, 0, 0}};
#pragma unroll
  for (int e = 0; e < 8; ++e) {
    int c = cidx[e];
    double p0 = pos[c * 3], p1 = pos[c * 3 + 1], p2 = pos[c * 3 + 2];
    double q0 = pred[c * 3], q1 = pred[c * 3 + 1], q2 = pred[c * 3 + 2];
    sp[0] += p0; sp[1] += p1; sp[2] += p2;
    sq[0] += q0; sq[1] += q1; sq[2] += q2;
    spq[0][0] += p0 * q0; spq[0][1] += p0 * q1; spq[0][2] += p0 * q2;
    spq[1][0] += p1 * q0; spq[1][1] += p1 * q1; spq[1][2] += p1 * q2;
    spq[2][0] += p2 * q0; spq[2][1] += p2 * q1; spq[2][2] += p2 * q2;
  }
  // butterfly reduce over the 4-lane group (xor 1, 2)
#pragma unroll
  for (int mask = 1; mask <= 2; mask <<= 1) {
#pragma unroll
    for (int a = 0; a < 3; ++a) {
      sp[a] += __shfl_xor(sp[a], mask);
      sq[a] += __shfl_xor(sq[a], mask);
#pragma unroll
      for (int b = 0; b < 3; ++b) spq[a][b] += __shfl_xor(spq[a][b], mask);
    }
  }

  const double inv = 1.0 / 32.0;
  double A[3][3], sc[3], tcn[3];
  for (int a = 0; a < 3; ++a) {
    sc[a] = sp[a] * inv;
    tcn[a] = sq[a] * inv;
  }
  for (int a = 0; a < 3; ++a)
    for (int b = 0; b < 3; ++b) A[a][b] = spq[a][b] - sp[a] * sq[b] * inv;

  double S[3][3];
  for (int a = 0; a < 3; ++a)
    for (int b = 0; b < 3; ++b)
      S[a][b] = A[0][a] * A[0][b] + A[1][a] * A[1][b] + A[2][a] * A[2][b];
  double V[3][3] = {{1, 0, 0}, {0, 1, 0}, {0, 0, 1}};
  const int JP[3] = {0, 0, 1}, JQ[3] = {1, 2, 2};
  for (int sweep = 0; sweep < 6; ++sweep) {
    for (int r = 0; r < 3; ++r) {
      int p = JP[r], q = JQ[r];
      double apq = S[p][q];
      if (fabs(apq) < 1e-300) continue;
      double theta = (S[q][q] - S[p][p]) / (2.0 * apq);
      double t2 = copysign(1.0 / (fabs(theta) + sqrt(theta * theta + 1.0)), theta);
      double c = 1.0 / sqrt(t2 * t2 + 1.0);
      double s = t2 * c;
      double spp = S[p][p], sqq = S[q][q];
      S[p][p] = spp - t2 * apq;
      S[q][q] = sqq + t2 * apq;
      S[p][q] = 0.0; S[q][p] = 0.0;
      int k = 3 - p - q;
      double skp = S[k][p], skq = S[k][q];
      S[k][p] = S[p][k] = c * skp - s * skq;
      S[k][q] = S[q][k] = s * skp + c * skq;
      for (int mth = 0; mth < 3; ++mth) {
        double vp = V[mth][p], vq = V[mth][q];
        V[mth][p] = c * vp - s * vq;
        V[mth][q] = s * vp + c * vq;
      }
    }
  }
  double lam[3] = {S[0][0], S[1][1], S[2][2]};
  int i0 = 0, i1 = 1, i2 = 2, tmp;
  if (lam[i0] < lam[i1]) { tmp = i0; i0 = i1; i1 = tmp; }
  if (lam[i0] < lam[i2]) { tmp = i0; i0 = i2; i2 = tmp; }
  if (lam[i1] < lam[i2]) { tmp = i1; i1 = i2; i2 = tmp; }
  double v0[3] = {V[0][i0], V[1][i0], V[2][i0]};
  double v1[3] = {V[0][i1], V[1][i1], V[2][i1]};
  double v2[3] = {V[0][i2], V[1][i2], V[2][i2]};

  double Av0[3], Av1[3], Av2[3];
  for (int a = 0; a < 3; ++a) {
    Av0[a] = A[a][0] * v0[0] + A[a][1] * v0[1] + A[a][2] * v0[2];
    Av1[a] = A[a][0] * v1[0] + A[a][1] * v1[1] + A[a][2] * v1[2];
    Av2[a] = A[a][0] * v2[0] + A[a][1] * v2[1] + A[a][2] * v2[2];
  }
  double n0 = fmax(sqrt(Av0[0]*Av0[0] + Av0[1]*Av0[1] + Av0[2]*Av0[2]), 1e-300);
  double u0[3] = {Av0[0] / n0, Av0[1] / n0, Av0[2] / n0};
  double proj = u0[0]*Av1[0] + u0[1]*Av1[1] + u0[2]*Av1[2];
  double u1[3] = {Av1[0] - proj * u0[0], Av1[1] - proj * u0[1], Av1[2] - proj * u0[2]};
  double n1 = fmax(sqrt(u1[0]*u1[0] + u1[1]*u1[1] + u1[2]*u1[2]), 1e-300);
  u1[0] /= n1; u1[1] /= n1; u1[2] /= n1;
  double w[3] = {u0[1]*u1[2] - u0[2]*u1[1],
                 u0[2]*u1[0] - u0[0]*u1[2],
                 u0[0]*u1[1] - u0[1]*u1[0]};
  double dotw = Av2[0]*w[0] + Av2[1]*w[1] + Av2[2]*w[2];
  double sgn = (dotw < 0.0) ? -1.0 : 1.0;
  double detA = A[0][0]*(A[1][1]*A[2][2] - A[1][2]*A[2][1])
              - A[0][1]*(A[1][0]*A[2][2] - A[1][2]*A[2][0])
              + A[0][2]*(A[1][0]*A[2][1] - A[1][1]*A[2][0]);
  double d3 = ((detA < 0.0) ? -1.0 : 1.0) * sgn;

  double R[3][3];
  for (int a = 0; a < 3; ++a)
    for (int b = 0; b < 3; ++b)
      R[a][b] = u0[a]*v0[b] + u1[a]*v1[b] + d3 * w[a]*v2[b];

  if (l == 0) {
    for (int a = 0; a < 3; ++a)
      for (int b = 0; b < 3; ++b) Rout[i * 9 + a * 3 + b] = (float)R[a][b];
    double tr_[3];
    for (int a = 0; a < 3; ++a) {
      tr_[a] = tcn[a] - (R[a][0]*sc[0] + R[a][1]*sc[1] + R[a][2]*sc[2]);
      tout[i * 3 + a] = (float)tr_[a];
    }
    double pxi = pos[i * 3], pyi = pos[i * 3 + 1], pzi = pos[i * 3 + 2];
    double r0 = R[0][0]*pxi + R[0][1]*pyi + R[0][2]*pzi + tr_[0] - pred[i * 3];
    double r1 = R[1][0]*pxi + R[1][1]*pyi + R[1][2]*pzi + tr_[1] - pred[i * 3 + 1];
    double r2 = R[2][0]*pxi + R[2][1]*pyi + R[2][2]*pzi + tr_[2] - pred[i * 3 + 2];
    qnorm[i] = (float)(r0 * r0 + r1 * r1 + r2 * r2);
  }
}

// ---------------- K3: per-node residual mean over neighbors ----------------
// 4 lanes/node (each gathers 8, butterfly xor 1,2) -> 1252 waves.
__global__ __launch_bounds__(256) void dst_kernel(
    const int* __restrict__ colp, const float* __restrict__ qn,
    float* __restrict__ dout) {
  int t = blockIdx.x * blockDim.x + threadIdx.x;
  int i = t >> 2;
  int l = t & 3;
  if (i >= NS) return;
  int4 cia[2];
#pragma unroll
  for (int tt = 0; tt < 2; ++tt)
    cia[tt] = reinterpret_cast<const int4*>(colp + (size_t)i * DEG + l * 8)[tt];
  const int* cidx = reinterpret_cast<const int*>(cia);
  float s = 0.f;
#pragma unroll
  for (int e = 0; e < 8; ++e) s += qn[cidx[e]];
  s += __shfl_xor(s, 1);
  s += __shfl_xor(s, 2);
  if (l == 0) dout[i] = s * (1.0f / 32.0f);
}

extern "C" void kernel_launch(void* const* d_in, const int* in_sizes, int n_in,
                              void* d_out, int out_size, void* d_ws, size_t ws_size,
                              hipStream_t stream) {
  const float* sf  = (const float*)d_in[0];   // [N,128]
  const float* tf  = (const float*)d_in[1];   // [T,128]
  const float* tp  = (const float*)d_in[2];   // [T,3]
  const float* pos = (const float*)d_in[3];   // [N,3]
  const int*   ei  = (const int*)d_in[4];     // [2,E]
  float* out = (float*)d_out;                 // [N*9 | N*3 | N]
  char* ws = (char*)d_ws;
  // ws layout (~5.9 MB; qn aliases tfbx which is dead after topk):
  float*          tn    = (float*)(ws);                    // 27,648 B
  float*          tn256 = (float*)(ws + 28672);            // 27,648 B
  float*          pred  = (float*)(ws + 57344);            // 240,000 B
  uint*           pkall = (uint*)(ws + 297344);            // 20000*24*4 = 1,920,000 B
  unsigned short* tfbx  = (unsigned short*)(ws + 4137344); // 1,769,472 B
  float*          qn    = (float*)(ws + 4137344);          // alias (post-topk)
  const int* colp = ei + EDG;

  tn_cast_kernel<<<(TPAD * 64) / 256, 256, 0, stream>>>(tf, tn, tn256, tfbx);
  topk_kernel<<<(NS / RPB) * NCB, 256, 0, stream>>>(sf, tfbx, tn256, pkall);
  merge_kernel<<<NS / 4, 256, 0, stream>>>(sf, tf, tn, pkall, tp, pred);
  proc_kernel<<<(NS * 4 + 255) / 256, 256, 0, stream>>>(colp, pos, pred, out,
                                                        out + NS * 9, qn);
  dst_kernel<<<(NS * 4 + 255) / 256, 256, 0, stream>>>(colp, qn, out + NS * 12);
}